// Round 3
// baseline (510.705 us; speedup 1.0000x reference)
//
#include <hip/hip_runtime.h>
#include <hip/hip_cooperative_groups.h>
#include <math.h>

namespace cg = cooperative_groups;

// ConnectedLossV4, fully fused single cooperative kernel.
// argmax -> per-class 4-connected components (min-index labels, union-find)
// -> placeholder (exact f32 op-order) -> per-target lower median via adaptive
// radix select (keys share exponent => usually ONE 2048-bin pass) -> counts ->
// bce+dice closed form. Background bce/dice continuous part fused into argmax.
//
// ws layout (N = B*H*W = 1048576):
//   [0,   4N)          parent int32 (union-find)
//   [4N,  8N)          keys   uint32 (placeholder f32 bit patterns)
//   [8N,  9N)          pk     uint8  (cls | tgt<<3)
//   [9N,  9N+18KB)     stats  uint32[4608]:
//     [0..7] cnt_class [8..15] cnt_target [16..23] ncomp
//     [32] presentBits [33] activeBits [34] n(c!=0,t==0) [35] n(c!=0,t!=0)
//     [40..47] median offset prefix  [48..55] krem(int)
//     [56..63] n11  [64..71] nfm  [72] minKeyBits [73] maxKeyBits
//     words 96..287: double dsl[3][32] (bg logsum / inter / sum_pred)
//   [9N+32KB, +57KB)   ghist uint32[7][2048]

#define HWMASK (262144 - 1)

static __device__ __forceinline__ int ufind(int* p, int x) {
  while (true) {
    int px = p[x];
    if (px == x) return x;
    int g = p[px];
    if (g == px) return px;
    p[x] = g;  // path halving (benign race)
    x = g;
  }
}

static __device__ __forceinline__ void unite(int* p, int a, int b) {
  while (true) {
    a = ufind(p, a); b = ufind(p, b);
    if (a == b) return;
    if (a < b) { int old = atomicCAS(&p[b], b, a); if (old == b) return; b = old; }
    else       { int old = atomicCAS(&p[a], a, b); if (old == a) return; a = old; }
  }
}

__global__ __launch_bounds__(256, 2) void k_fused(
    const float* __restrict__ pred, const int* __restrict__ tgt,
    int* __restrict__ parent, unsigned* __restrict__ keys,
    unsigned char* __restrict__ pk, unsigned* __restrict__ stats,
    unsigned* __restrict__ ghist, float* __restrict__ out, int N) {
  cg::grid_group grid = cg::this_grid();
  __shared__ unsigned lh[14336];   // 7 targets x 2048 bins (also scan scratch)
  __shared__ unsigned sw[40];
  __shared__ double dred[12];
  const int tid = threadIdx.x;
  const int gsz = gridDim.x * blockDim.x;
  const int gtid = blockIdx.x * blockDim.x + tid;
  const int n4 = N >> 2;

  // ---- Phase A: zero stats + ghist --------------------------------------
  for (int i = gtid; i < 4608; i += gsz) stats[i] = (i == 72) ? 0xFFFFFFFFu : 0u;
  for (int i = gtid; i < 14336; i += gsz) ghist[i] = 0u;
  grid.sync();

  // ---- Phase B: argmax + bg term + class/target counts ------------------
  {
    if (tid < 8) { sw[tid] = 0; sw[8 + tid] = 0; }
    if (tid == 0) { sw[16] = 0; sw[17] = 0; }
    __syncthreads();
    double aL = 0.0, aI = 0.0, aP = 0.0;
    unsigned nA = 0, nB = 0;
    for (int i4 = gtid; i4 < n4; i4 += gsz) {
      int i = i4 << 2;
      int b = i >> 18, hw = i & HWMASK;
      const float* pp = pred + ((size_t)b << 21) + hw;
      float4 v[8];
#pragma unroll
      for (int ch = 0; ch < 8; ++ch) v[ch] = *(const float4*)(pp + ((size_t)ch << 18));
      int4 tv = *(const int4*)(tgt + i);
      int tarr[4] = {tv.x & 7, tv.y & 7, tv.z & 7, tv.w & 7};
      unsigned char pkb[4];
#pragma unroll
      for (int j = 0; j < 4; ++j) {
        float p0 = ((const float*)&v[0])[j];
        float best = p0; int c = 0;
#pragma unroll
        for (int ch = 1; ch < 8; ++ch) {        // first-max == numpy argmax
          float x = ((const float*)&v[ch])[j];
          if (x > best) { best = x; c = ch; }
        }
        int t = tarr[j];
        pkb[j] = (unsigned char)(c | (t << 3));
        atomicAdd(&sw[c], 1u);
        atomicAdd(&sw[8 + t], 1u);
        if (c == 0) {                           // continuous bg term
          float pc = fminf(fmaxf(p0, 1e-7f), 1.0f - 1e-7f);
          if (t == 0) { aL += (double)logf(pc); aI += (double)p0; }
          else        { aL += (double)logf(1.0f - pc); }
          aP += (double)p0;
        } else { if (t == 0) nA++; else nB++; } // pv==0 -> constant log, count
      }
      *(int4*)(parent + i) = make_int4(i, i + 1, i + 2, i + 3);
      *(uchar4*)(pk + i) = make_uchar4(pkb[0], pkb[1], pkb[2], pkb[3]);
    }
    if (nA) atomicAdd(&sw[16], nA);
    if (nB) atomicAdd(&sw[17], nB);
#pragma unroll
    for (int o = 32; o > 0; o >>= 1) {
      aL += __shfl_down(aL, o); aI += __shfl_down(aI, o); aP += __shfl_down(aP, o);
    }
    int wid = tid >> 6, lane = tid & 63;
    if (lane == 0) { dred[wid] = aL; dred[4 + wid] = aI; dred[8 + wid] = aP; }
    __syncthreads();
    if (tid == 0) {
      double* dsl = (double*)(stats + 96);
      int s = blockIdx.x & 31;
      atomicAdd(&dsl[s],      dred[0] + dred[1] + dred[2] + dred[3]);
      atomicAdd(&dsl[32 + s], dred[4] + dred[5] + dred[6] + dred[7]);
      atomicAdd(&dsl[64 + s], dred[8] + dred[9] + dred[10] + dred[11]);
      if (sw[16]) atomicAdd(&stats[34], sw[16]);
      if (sw[17]) atomicAdd(&stats[35], sw[17]);
    }
    if (tid < 8) {
      if (sw[tid])     atomicAdd(&stats[tid], sw[tid]);
      if (sw[8 + tid]) atomicAdd(&stats[8 + tid], sw[8 + tid]);
    }
  }
  grid.sync();

  // ---- Phase C: union-find merge ----------------------------------------
  for (int i = gtid; i < N; i += gsz) {
    int c = pk[i] & 7;
    if (!c) continue;
    int hw = i & HWMASK;
    if ((hw & 511) < 511 && (pk[i + 1] & 7) == c)   unite(parent, i, i + 1);
    if ((hw >> 9) < 511 && (pk[i + 512] & 7) == c)  unite(parent, i, i + 512);
  }
  grid.sync();

  // ---- Phase D: flatten + component counts ------------------------------
  {
    if (tid < 8) sw[tid] = 0;
    __syncthreads();
    for (int i = gtid; i < N; i += gsz) {
      int c = pk[i] & 7;
      if (!c) continue;
      int r = ufind(parent, i);
      parent[i] = r;
      if (r == i) atomicAdd(&sw[c], 1u);   // representative (min idx) per comp
    }
    __syncthreads();
    if (tid < 8 && sw[tid]) atomicAdd(&stats[16 + tid], sw[tid]);
  }
  grid.sync();

  // ---- Phase E: scalars, replicated per block (no extra grid sync) ------
  {
    if (tid == 0) {
      float* sprod = (float*)&sw[0];
      int last_i = 1; unsigned pb = 0;
      for (int v = 1; v < 8; ++v) {
        unsigned cntv = stats[v], ncv = stats[16 + v];
        if (cntv) {
          sprod[v] = __fmul_rn((float)ncv, (float)last_i);  // exact ref rounding
          pb |= 1u << v;
          last_i += (int)ncv + ((cntv < (unsigned)N) ? 1 : 0);  // + has_bg
        } else sprod[v] = 0.0f;
      }
      sw[16] = pb;
      unsigned ab = 0;
      for (int t = 1; t < 8; ++t) if (stats[8 + t]) ab |= 1u << t;
      sw[17] = ab;
      if (blockIdx.x == 0) {
        stats[32] = pb; stats[33] = ab;
        for (int t = 1; t < 8; ++t) {
          unsigned n = stats[8 + t];
          ((int*)stats)[48 + t] = n ? (int)((n - 1) >> 1) : -1;  // lower median
        }
      }
    }
    __syncthreads();
  }

  // ---- Phase F: placeholder keys + global key min/max -------------------
  {
    if (tid == 0) { sw[30] = 0xFFFFFFFFu; sw[31] = 0u; }
    __syncthreads();
    const float* sprod = (const float*)&sw[0];
    unsigned pb = sw[16];
    unsigned kmin = 0xFFFFFFFFu, kmax = 0u;
    for (int i4 = gtid; i4 < n4; i4 += gsz) {
      int i = i4 << 2;
      int4 pr = *(const int4*)(parent + i);
      uchar4 pv = *(const uchar4*)(pk + i);
      int parr[4] = {pr.x, pr.y, pr.z, pr.w};
      int carr[4] = {pv.x & 7, pv.y & 7, pv.z & 7, pv.w & 7};
      unsigned ko[4];
#pragma unroll
      for (int j = 0; j < 4; ++j) {
        int c = carr[j];
        float lab = c ? (float)(parr[j] + 1) : 0.0f;   // < 2^24, exact
        float ph = 0.0f;
#pragma unroll
        for (int v = 1; v < 8; ++v) {                  // exact numpy op order
          if (pb & (1u << v)) {
            float term = sprod[v];
            if (c == v) term = __fadd_rn(lab, term);
            ph = __fadd_rn(ph, term);
          }
        }
        unsigned kb = __float_as_uint(ph);             // ph>=0: uint order==float order
        ko[j] = kb;
        kmin = min(kmin, kb); kmax = max(kmax, kb);
      }
      *(uint4*)(keys + i) = make_uint4(ko[0], ko[1], ko[2], ko[3]);
    }
    atomicMin(&sw[30], kmin); atomicMax(&sw[31], kmax);
    __syncthreads();
    if (tid == 0) { atomicMin(&stats[72], sw[30]); atomicMax(&stats[73], sw[31]); }
  }
  grid.sync();

  // ---- Radix select loop (usually a single pass since keys share exponent)
  const unsigned abm = sw[17];
  const unsigned minb = stats[72];
  {
    unsigned R = stats[73] - minb;
    int bl = 32 - __clz((int)R);            // bit length; R==0 -> 0
    int s = (bl > 11) ? (bl - 11) : 0;      // smallest s with (R>>s) < 2048
    unsigned maskhi = 0u;
    while (true) {
      if (tid < 8) sw[20 + tid] = stats[40 + tid];   // per-target prefix P_t
      for (int j = tid; j < 14336; j += blockDim.x) lh[j] = 0;
      __syncthreads();
      for (int i4 = gtid; i4 < n4; i4 += gsz) {
        int i = i4 << 2;
        uint4 kv = *(const uint4*)(keys + i);
        uchar4 pv = *(const uchar4*)(pk + i);
        unsigned karr[4] = {kv.x, kv.y, kv.z, kv.w};
        int tarr[4] = {pv.x >> 3, pv.y >> 3, pv.z >> 3, pv.w >> 3};
#pragma unroll
        for (int j = 0; j < 4; ++j) {
          int t = tarr[j];
          if (t && (abm >> t & 1u)) {
            unsigned off = karr[j] - minb;
            if (((off ^ sw[20 + t]) & maskhi) == 0u)
              atomicAdd(&lh[((t - 1) << 11) | ((off >> s) & 2047u)], 1u);
          }
        }
      }
      __syncthreads();
      for (int j = tid; j < 14336; j += blockDim.x) {
        unsigned v = lh[j];
        if (v) atomicAdd(&ghist[j], v);
      }
      grid.sync();
      if (blockIdx.x == 0) {                 // scan: find median bin per target
        for (int t = 1; t < 8; ++t) {
          if (!(abm >> t & 1u)) continue;
          int k = ((int*)stats)[48 + t];
          unsigned* h = ghist + ((t - 1) << 11);
          int base = tid << 3;
          unsigned loc[8]; unsigned sm = 0;
#pragma unroll
          for (int j = 0; j < 8; ++j) { loc[j] = h[base + j]; sm += loc[j]; }
          lh[tid] = sm;
          __syncthreads();
          for (int o2 = 1; o2 < 256; o2 <<= 1) {   // inclusive Hillis-Steele
            unsigned v = (tid >= o2) ? lh[tid - o2] : 0u;
            __syncthreads();
            lh[tid] += v;
            __syncthreads();
          }
          unsigned incl = lh[tid], excl = incl - sm;
          if ((unsigned)k >= excl && (unsigned)k < incl) {  // unique owner
            unsigned cum = excl;
#pragma unroll
            for (int j = 0; j < 8; ++j) {
              unsigned c = loc[j];
              if (cum + c > (unsigned)k) {
                stats[40 + t] |= ((unsigned)(base + j)) << s;
                ((int*)stats)[48 + t] = k - (int)cum;
                break;
              }
              cum += c;
            }
          }
          __syncthreads();
        }
        if (s > 0) for (int j = tid; j < 14336; j += 256) ghist[j] = 0;
      }
      grid.sync();
      if (s == 0) break;                    // uniform: all blocks agree
      maskhi = 0xFFFFFFFFu << s;
      s = (s > 11) ? (s - 11) : 0;
    }
  }

  // ---- Phase J: median-match counts -------------------------------------
  {
    if (tid < 8) { sw[tid] = 0; sw[8 + tid] = 0; sw[20 + tid] = minb + stats[40 + tid]; }
    __syncthreads();
    for (int i4 = gtid; i4 < n4; i4 += gsz) {
      int i = i4 << 2;
      uint4 kv = *(const uint4*)(keys + i);
      uchar4 pv = *(const uchar4*)(pk + i);
      unsigned karr[4] = {kv.x, kv.y, kv.z, kv.w};
      int tarr[4] = {pv.x >> 3, pv.y >> 3, pv.z >> 3, pv.w >> 3};
#pragma unroll
      for (int j = 0; j < 4; ++j) {
        unsigned kb = karr[j];
        int t = tarr[j];
#pragma unroll
        for (int tt = 1; tt < 8; ++tt) {
          if ((abm >> tt & 1u) && kb == sw[20 + tt]) {
            atomicAdd(&sw[8 + tt], 1u);
            if (t == tt) atomicAdd(&sw[tt], 1u);
          }
        }
      }
    }
    __syncthreads();
    if (tid < 8) {
      if (sw[8 + tid]) atomicAdd(&stats[64 + tid], sw[8 + tid]);  // |full_med|
      if (sw[tid])     atomicAdd(&stats[56 + tid], sw[tid]);      // n11
    }
  }
  grid.sync();

  // ---- Phase K: finalize -------------------------------------------------
  if (blockIdx.x == 0 && tid < 64) {
    const double* dsl = (const double*)(stats + 96);
    double vL = 0.0, vI = 0.0, vP = 0.0;
    if (tid < 32) { vL = dsl[tid]; vI = dsl[32 + tid]; vP = dsl[64 + tid]; }
#pragma unroll
    for (int o = 32; o > 0; o >>= 1) {
      vL += __shfl_down(vL, o); vI += __shfl_down(vI, o); vP += __shfl_down(vP, o);
    }
    if (tid == 0) {
      double Nd = (double)N;
      const float e32 = 1e-7f;
      const float c1 = 1.0f - e32;          // clip upper (f32)
      const float omc1 = 1.0f - c1;
      double lp1 = log((double)c1);
      double lp0 = log((double)e32);
      double l01 = log((double)omc1);
      double l00 = lp1;
      double L = vL + (double)stats[34] * lp0 + (double)stats[35] * l00;
      double res = -L / Nd;                                                 // bce_bg
      res += 1.0 - (2.0 * vI + 1.0) / (vP + (double)stats[8] + 1.0);        // dice_bg
      unsigned ab = stats[33];
      for (int t = 1; t < 8; ++t) {
        if (ab >> t & 1u) {
          double a = (double)stats[56 + t];
          double f = (double)stats[64 + t];
          double n = (double)stats[8 + t];
          double bce = -(a * lp1 + (n - a) * lp0 + (f - a) * l01 + (Nd - n - f + a) * l00) / Nd;
          double dice = 1.0 - (2.0 * a + 1.0) / (f + n + 1.0);
          res += bce + dice;
        }
      }
      int nu = 0;
      for (int t = 0; t < 8; ++t) nu += (stats[8 + t] > 0);
      out[0] = (float)(res / ((double)nu + 1.0));
    }
  }
}

extern "C" void kernel_launch(void* const* d_in, const int* in_sizes, int n_in,
                              void* d_out, int out_size, void* d_ws, size_t ws_size,
                              hipStream_t stream) {
  const float* pred = (const float*)d_in[0];   // [B,8,512,512] f32
  const int* tgt = (const int*)d_in[1];        // [B,1,512,512] i32
  int N = in_sizes[1];                         // B*H*W
  char* ws = (char*)d_ws;
  int* parent = (int*)ws;
  unsigned* keys = (unsigned*)(ws + (size_t)N * 4);
  unsigned char* pk = (unsigned char*)(ws + (size_t)N * 8);
  unsigned* stats = (unsigned*)(ws + (size_t)N * 9);
  unsigned* ghist = (unsigned*)(ws + (size_t)N * 9 + 32768);
  float* out = (float*)d_out;

  int dev = 0;
  hipGetDevice(&dev);
  int nCU = 256, maxPerCU = 0;
  hipDeviceGetAttribute(&nCU, hipDeviceAttributeMultiprocessorCount, dev);
  hipOccupancyMaxActiveBlocksPerMultiprocessor(&maxPerCU, k_fused, 256, 0);
  int g = maxPerCU * nCU;
  if (g > 512) g = 512;
  if (g < 1) g = 1;

  void* args[9];
  args[0] = (void*)&pred; args[1] = (void*)&tgt;   args[2] = (void*)&parent;
  args[3] = (void*)&keys; args[4] = (void*)&pk;    args[5] = (void*)&stats;
  args[6] = (void*)&ghist; args[7] = (void*)&out;  args[8] = (void*)&N;
  hipLaunchCooperativeKernel(k_fused, dim3(g), dim3(256), args, 0, stream);
}

// Round 4
// 192.251 us; speedup vs baseline: 2.6564x; 2.6564x over previous
//
#include <hip/hip_runtime.h>
#include <math.h>

// ConnectedLossV4, 8-node graph (grid barriers = kernel boundaries; cg::grid.sync
// measured ~55us/sync on MI355X due to cross-XCD L2 WB/INV -> abandoned).
//   1 k_zero       zero stats+ghist (own kernel; rocclr fill showed odd 40us cases)
//   2 k_argmax     argmax + bg-bce/dice continuous part + class/target counts
//   3 k_merge      4-connected union-find (min-root CAS)
//   4 k_flatten    path-compress + ncomp; LAST BLOCK computes scalars (prodf,
//                  pb/ab, ph0 anchor, s1 window, median ranks)
//   5 k_ph_hist    placeholder keys (exact f32 op order) + radix pass 1
//                  anchored at ph0 (keys>=ph0 by rounding monotonicity; window
//                  bound from ph0's exponent) ; LAST BLOCK scans -> median bin
//   6 k_histp(2)   early-exit stub unless window needed >11 bits
//   7 k_histp(3)   early-exit stub (s always resolves by pass 3)
//   8 k_med        median-match counts; LAST BLOCK -> closed-form bce+dice -> out
//
// ws layout (N = B*H*W = 1048576):
//   [0,4N) parent | [4N,8N) keys | [8N,9N) pk = cls|tgt<<3 | [9N,..) stats+ghist
// stats words: 0..7 cntClass, 8..15 cntTarget, 16..23 ncomp, 24..31 prodf bits,
//   32 pb, 33 ab, 34 n(c!=0,t=0), 35 n(c!=0,t!=0), 36 ph0 bits, 37 s1,
//   38 resolved, 40..47 median-offset prefix, 48..55 krem, 56..63 n11,
//   64..71 nfm, 76..80 arrival counters, 96.. dsl double[3][32].
//   ghist = stats + 8192 words, uint32[7][2048].

#define HWMASK (262144 - 1)
#define AL(p) __hip_atomic_load((p), __ATOMIC_RELAXED, __HIP_MEMORY_SCOPE_AGENT)

static __device__ __forceinline__ int ufind(int* p, int x) {
  while (true) {
    int px = p[x];
    if (px == x) return x;
    int g = p[px];
    if (g == px) return px;
    p[x] = g;  // path halving (benign race)
    x = g;
  }
}

static __device__ __forceinline__ void unite(int* p, int a, int b) {
  while (true) {
    a = ufind(p, a); b = ufind(p, b);
    if (a == b) return;
    if (a < b) { int old = atomicCAS(&p[b], b, a); if (old == b) return; b = old; }
    else       { int old = atomicCAS(&p[a], a, b); if (old == a) return; a = old; }
  }
}

__global__ void k_zero(unsigned* __restrict__ stats) {
  int i = blockIdx.x * blockDim.x + threadIdx.x;
  if (i < 22528) stats[i] = 0u;   // 8192 stats + 14336 ghist
}

__global__ void k_argmax(const float* __restrict__ pred, const int* __restrict__ tgt,
                         int* __restrict__ parent, unsigned char* __restrict__ pk,
                         unsigned* __restrict__ stats, int N) {
  __shared__ unsigned hc[8], ht[8], hA, hB;
  __shared__ double dred[12];
  int tid = threadIdx.x;
  if (tid < 8) { hc[tid] = 0; ht[tid] = 0; }
  if (tid == 0) { hA = 0; hB = 0; }
  __syncthreads();
  int n4 = N >> 2;
  int gsz = gridDim.x * blockDim.x;
  double aL = 0.0, aI = 0.0, aP = 0.0;
  unsigned nA = 0, nB = 0;
  for (int i4 = blockIdx.x * blockDim.x + tid; i4 < n4; i4 += gsz) {
    int i = i4 << 2;
    int b = i >> 18, hw = i & HWMASK;
    const float* pp = pred + ((size_t)b << 21) + hw;
    float4 v[8];
#pragma unroll
    for (int ch = 0; ch < 8; ++ch) v[ch] = *(const float4*)(pp + ((size_t)ch << 18));
    int4 tv = *(const int4*)(tgt + i);
    int tarr[4] = {tv.x & 7, tv.y & 7, tv.z & 7, tv.w & 7};
    unsigned char pkb[4];
#pragma unroll
    for (int j = 0; j < 4; ++j) {
      float p0 = ((const float*)&v[0])[j];
      float best = p0; int c = 0;
#pragma unroll
      for (int ch = 1; ch < 8; ++ch) {          // first-max == numpy argmax
        float x = ((const float*)&v[ch])[j];
        if (x > best) { best = x; c = ch; }
      }
      int t = tarr[j];
      pkb[j] = (unsigned char)(c | (t << 3));
      atomicAdd(&hc[c], 1u);
      atomicAdd(&ht[t], 1u);
      if (c == 0) {                             // continuous bg term
        float pc = fminf(fmaxf(p0, 1e-7f), 1.0f - 1e-7f);
        if (t == 0) { aL += (double)logf(pc); aI += (double)p0; }
        else        { aL += (double)logf(1.0f - pc); }
        aP += (double)p0;
      } else { if (t == 0) nA++; else nB++; }   // pv==0 -> constant log, count
    }
    *(int4*)(parent + i) = make_int4(i, i + 1, i + 2, i + 3);
    *(uchar4*)(pk + i) = make_uchar4(pkb[0], pkb[1], pkb[2], pkb[3]);
  }
  if (nA) atomicAdd(&hA, nA);
  if (nB) atomicAdd(&hB, nB);
#pragma unroll
  for (int o = 32; o > 0; o >>= 1) {
    aL += __shfl_down(aL, o); aI += __shfl_down(aI, o); aP += __shfl_down(aP, o);
  }
  int wid = tid >> 6, lane = tid & 63;
  if (lane == 0) { dred[wid] = aL; dred[4 + wid] = aI; dred[8 + wid] = aP; }
  __syncthreads();
  if (tid == 0) {
    double* dsl = (double*)(stats + 96);
    int s = blockIdx.x & 31;
    atomicAdd(&dsl[s],      dred[0] + dred[1] + dred[2] + dred[3]);
    atomicAdd(&dsl[32 + s], dred[4] + dred[5] + dred[6] + dred[7]);
    atomicAdd(&dsl[64 + s], dred[8] + dred[9] + dred[10] + dred[11]);
    if (hA) atomicAdd(&stats[34], hA);
    if (hB) atomicAdd(&stats[35], hB);
  }
  if (tid < 8) {
    if (hc[tid]) atomicAdd(&stats[tid], hc[tid]);
    if (ht[tid]) atomicAdd(&stats[8 + tid], ht[tid]);
  }
}

__global__ void k_merge(const unsigned char* __restrict__ pk, int* __restrict__ parent, int N) {
  int gsz = gridDim.x * blockDim.x;
  for (int i = blockIdx.x * blockDim.x + threadIdx.x; i < N; i += gsz) {
    int c = pk[i] & 7;
    if (!c) continue;
    int hw = i & HWMASK;
    if ((hw & 511) < 511 && (pk[i + 1] & 7) == c)   unite(parent, i, i + 1);
    if ((hw >> 9) < 511 && (pk[i + 512] & 7) == c)  unite(parent, i, i + 512);
  }
}

__global__ void k_flatten(const unsigned char* __restrict__ pk, int* __restrict__ parent,
                          unsigned* __restrict__ stats, int N) {
  __shared__ unsigned nc[8];
  __shared__ int lastF;
  int tid = threadIdx.x;
  if (tid < 8) nc[tid] = 0;
  __syncthreads();
  int gsz = gridDim.x * blockDim.x;
  for (int i = blockIdx.x * blockDim.x + tid; i < N; i += gsz) {
    int c = pk[i] & 7;
    if (!c) continue;
    int r = ufind(parent, i);
    parent[i] = r;
    if (r == i) atomicAdd(&nc[c], 1u);   // representative (min idx) per comp
  }
  __syncthreads();
  if (tid < 8 && nc[tid]) atomicAdd(&stats[16 + tid], nc[tid]);
  __syncthreads();  // barrier drains each wave's outstanding atomics
  if (tid == 0) {
    unsigned prev = __hip_atomic_fetch_add(&stats[76], 1u, __ATOMIC_ACQ_REL,
                                           __HIP_MEMORY_SCOPE_AGENT);
    lastF = (prev == gridDim.x - 1);
  }
  __syncthreads();
  if (!lastF || tid != 0) return;
  // ---- scalars (single thread; ~100 ops) --------------------------------
  unsigned cntc[8], nco[8], cntt[8];
  for (int v = 0; v < 8; ++v) {
    cntc[v] = AL(&stats[v]); nco[v] = AL(&stats[16 + v]); cntt[v] = AL(&stats[8 + v]);
  }
  float prodf[8]; int last_i = 1; unsigned pb = 0;
  for (int v = 1; v < 8; ++v) {
    prodf[v] = 0.0f;
    if (cntc[v]) {
      prodf[v] = __fmul_rn((float)nco[v], (float)last_i);   // exact ref rounding
      pb |= 1u << v;
      last_i += (int)nco[v] + ((cntc[v] < (unsigned)N) ? 1 : 0);  // + has_bg
    }
    stats[24 + v] = __float_as_uint(prodf[v]);
  }
  float ph0 = 0.0f;   // background key (min key: rounding is monotone)
  for (int v = 1; v < 8; ++v) if (pb & (1u << v)) ph0 = __fadd_rn(ph0, prodf[v]);
  unsigned ab = 0;
  for (int t = 1; t < 8; ++t) {
    unsigned n = cntt[t];
    ((int*)stats)[48 + t] = n ? (int)((n - 1) >> 1) : -1;   // lower-median rank
    if (n) ab |= 1u << t;
  }
  stats[32] = pb; stats[33] = ab;
  unsigned pbits = __float_as_uint(ph0);
  stats[36] = pbits;
  // key-code window bound: codes in (ph0, ph0+2^20] <= 2^(43-e), e=exp(ph0)
  unsigned c;
  if (pbits == 0) c = 64u;
  else {
    int e = (int)(pbits >> 23) - 127;
    int sh = 43 - e;
    if (sh <= 0) c = 64u;
    else if (sh >= 31) c = 0x7FFFFFFFu;
    else c = (1u << sh) + 64u;
  }
  int bl = 32 - __clz((int)c);
  stats[37] = (bl > 11) ? (unsigned)(bl - 11) : 0u;   // s1
}

static __device__ void scan_select(unsigned* __restrict__ stats, unsigned* __restrict__ ghist,
                                   unsigned abm, int s_cur, unsigned* lh) {
  int tid = threadIdx.x;
  for (int t = 1; t < 8; ++t) {
    if (!(abm >> t & 1u)) continue;
    int k = ((int*)stats)[48 + t];
    unsigned* h = ghist + ((t - 1) << 11);
    int base = tid << 3;
    unsigned loc[8]; unsigned sm = 0;
#pragma unroll
    for (int j = 0; j < 8; ++j) { loc[j] = AL(&h[base + j]); sm += loc[j]; }
    lh[tid] = sm;
    __syncthreads();
    for (int o = 1; o < 256; o <<= 1) {   // inclusive Hillis-Steele
      unsigned v = (tid >= o) ? lh[tid - o] : 0u;
      __syncthreads();
      lh[tid] += v;
      __syncthreads();
    }
    unsigned incl = lh[tid], excl = incl - sm;
    if ((unsigned)k >= excl && (unsigned)k < incl) {   // unique owner
      unsigned cum = excl;
#pragma unroll
      for (int j = 0; j < 8; ++j) {
        unsigned cc = loc[j];
        if (cum + cc > (unsigned)k) {
          stats[40 + t] |= ((unsigned)(base + j)) << s_cur;
          ((int*)stats)[48 + t] = k - (int)cum;
          break;
        }
        cum += cc;
      }
    }
    __syncthreads();
  }
}

__global__ __launch_bounds__(256) void k_ph_hist(
    const unsigned char* __restrict__ pk, const int* __restrict__ parent,
    unsigned* __restrict__ keys, unsigned* __restrict__ stats,
    unsigned* __restrict__ ghist, int N) {
  __shared__ unsigned lh[14336];
  __shared__ float sprod[8];
  __shared__ unsigned sb[8];
  int tid = threadIdx.x;
  if (tid < 8) sprod[tid] = __uint_as_float(stats[24 + tid]);
  if (tid == 0) { sb[0] = stats[32]; sb[1] = stats[33]; sb[2] = stats[36]; sb[3] = stats[37]; }
  for (int j = tid; j < 14336; j += blockDim.x) lh[j] = 0u;
  __syncthreads();
  unsigned pb = sb[0], ab = sb[1], ph0 = sb[2];
  int s1 = (int)sb[3];
  int n4 = N >> 2, gsz = gridDim.x * blockDim.x;
  for (int i4 = blockIdx.x * blockDim.x + tid; i4 < n4; i4 += gsz) {
    int i = i4 << 2;
    int4 pr = *(const int4*)(parent + i);
    uchar4 pv = *(const uchar4*)(pk + i);
    int parr[4] = {pr.x, pr.y, pr.z, pr.w};
    unsigned char pa[4] = {pv.x, pv.y, pv.z, pv.w};
    unsigned ko[4];
#pragma unroll
    for (int j = 0; j < 4; ++j) {
      int c = pa[j] & 7, t = pa[j] >> 3;
      float lab = c ? (float)(parr[j] + 1) : 0.0f;   // < 2^24, exact
      float ph = 0.0f;
#pragma unroll
      for (int v = 1; v < 8; ++v) {                  // exact numpy op order
        if (pb & (1u << v)) {
          float term = sprod[v];
          if (c == v) term = __fadd_rn(lab, term);
          ph = __fadd_rn(ph, term);
        }
      }
      unsigned kb = __float_as_uint(ph);
      ko[j] = kb;
      if (t && (ab >> t & 1u)) {                     // radix pass 1, anchored
        unsigned off = kb - ph0;                     // >= 0 by monotonicity
        unsigned bin = off >> s1;
        if (bin > 2047u) bin = 2047u;                // belt-and-braces
        atomicAdd(&lh[((t - 1) << 11) | bin], 1u);
      }
    }
    *(uint4*)(keys + i) = make_uint4(ko[0], ko[1], ko[2], ko[3]);
  }
  __syncthreads();
  for (int j = tid; j < 14336; j += blockDim.x) {
    unsigned v = lh[j];
    if (v) atomicAdd(&ghist[j], v);
  }
  __syncthreads();
  if (tid == 0) {
    unsigned prev = __hip_atomic_fetch_add(&stats[77], 1u, __ATOMIC_ACQ_REL,
                                           __HIP_MEMORY_SCOPE_AGENT);
    sb[4] = (prev == gridDim.x - 1) ? 1u : 0u;
  }
  __syncthreads();
  if (!sb[4]) return;
  scan_select(stats, ghist, ab, s1, lh);
  if (tid == 0) stats[38] = (s1 == 0) ? 1u : 0u;
  if (s1 > 0) for (int j = tid; j < 14336; j += blockDim.x) ghist[j] = 0u;
}

__global__ __launch_bounds__(256) void k_histp(
    const unsigned* __restrict__ keys, const unsigned char* __restrict__ pk,
    unsigned* __restrict__ stats, unsigned* __restrict__ ghist, int N, int pass) {
  __shared__ unsigned lh[14336];
  __shared__ unsigned sb[16];
  int tid = threadIdx.x;
  if (tid < 8) sb[8 + tid] = stats[40 + tid];
  if (tid == 0) { sb[0] = stats[38]; sb[1] = stats[33]; sb[2] = stats[36]; sb[3] = stats[37]; }
  __syncthreads();
  if (sb[0]) return;                       // already resolved -> stub
  unsigned ab = sb[1], ph0 = sb[2];
  int s1 = (int)sb[3];
  int sprev = s1 - 11 * (pass - 2); if (sprev < 0) sprev = 0;
  int scur  = s1 - 11 * (pass - 1); if (scur  < 0) scur  = 0;
  unsigned maskhi = 0xFFFFFFFFu << sprev;  // sprev >= 1 when unresolved
  for (int j = tid; j < 14336; j += blockDim.x) lh[j] = 0u;
  __syncthreads();
  int n4 = N >> 2, gsz = gridDim.x * blockDim.x;
  for (int i4 = blockIdx.x * blockDim.x + tid; i4 < n4; i4 += gsz) {
    int i = i4 << 2;
    uint4 kv = *(const uint4*)(keys + i);
    uchar4 pv = *(const uchar4*)(pk + i);
    unsigned karr[4] = {kv.x, kv.y, kv.z, kv.w};
    unsigned char pa[4] = {pv.x, pv.y, pv.z, pv.w};
#pragma unroll
    for (int j = 0; j < 4; ++j) {
      int t = pa[j] >> 3;
      if (t && (ab >> t & 1u)) {
        unsigned off = karr[j] - ph0;
        if (((off ^ sb[8 + t]) & maskhi) == 0u)
          atomicAdd(&lh[((t - 1) << 11) | ((off >> scur) & 2047u)], 1u);
      }
    }
  }
  __syncthreads();
  for (int j = tid; j < 14336; j += blockDim.x) {
    unsigned v = lh[j];
    if (v) atomicAdd(&ghist[j], v);
  }
  __syncthreads();
  if (tid == 0) {
    unsigned prev = __hip_atomic_fetch_add(&stats[76 + pass], 1u, __ATOMIC_ACQ_REL,
                                           __HIP_MEMORY_SCOPE_AGENT);
    sb[4] = (prev == gridDim.x - 1) ? 1u : 0u;
  }
  __syncthreads();
  if (!sb[4]) return;
  scan_select(stats, ghist, ab, scur, lh);
  if (tid == 0) stats[38] = (scur == 0) ? 1u : 0u;
  if (scur > 0) for (int j = tid; j < 14336; j += blockDim.x) ghist[j] = 0u;
}

__global__ __launch_bounds__(256) void k_med(
    const unsigned* __restrict__ keys, const unsigned char* __restrict__ pk,
    unsigned* __restrict__ stats, float* __restrict__ out, int N) {
  __shared__ unsigned s11[8], sfm[8], smed[8], sab;
  __shared__ int lastF;
  int tid = threadIdx.x;
  if (tid < 8) { s11[tid] = 0; sfm[tid] = 0; smed[tid] = stats[36] + stats[40 + tid]; }
  if (tid == 0) sab = stats[33];
  __syncthreads();
  unsigned ab = sab;
  int n4 = N >> 2, gsz = gridDim.x * blockDim.x;
  for (int i4 = blockIdx.x * blockDim.x + tid; i4 < n4; i4 += gsz) {
    int i = i4 << 2;
    uint4 kv = *(const uint4*)(keys + i);
    uchar4 pv = *(const uchar4*)(pk + i);
    unsigned karr[4] = {kv.x, kv.y, kv.z, kv.w};
    unsigned char pa[4] = {pv.x, pv.y, pv.z, pv.w};
#pragma unroll
    for (int j = 0; j < 4; ++j) {
      unsigned kb = karr[j];
      int t = pa[j] >> 3;
#pragma unroll
      for (int tt = 1; tt < 8; ++tt) {
        if ((ab >> tt & 1u) && kb == smed[tt]) {
          atomicAdd(&sfm[tt], 1u);
          if (t == tt) atomicAdd(&s11[tt], 1u);
        }
      }
    }
  }
  __syncthreads();
  if (tid < 8) {
    if (sfm[tid]) atomicAdd(&stats[64 + tid], sfm[tid]);   // |full_med|
    if (s11[tid]) atomicAdd(&stats[56 + tid], s11[tid]);   // n11
  }
  __syncthreads();
  if (tid == 0) {
    unsigned prev = __hip_atomic_fetch_add(&stats[80], 1u, __ATOMIC_ACQ_REL,
                                           __HIP_MEMORY_SCOPE_AGENT);
    lastF = (prev == gridDim.x - 1);
  }
  __syncthreads();
  if (!lastF || tid >= 64) return;
  // ---- finalize ----------------------------------------------------------
  const double* dsl = (const double*)(stats + 96);
  double vL = 0.0, vI = 0.0, vP = 0.0;
  if (tid < 32) { vL = dsl[tid]; vI = dsl[32 + tid]; vP = dsl[64 + tid]; }
#pragma unroll
  for (int o = 32; o > 0; o >>= 1) {
    vL += __shfl_down(vL, o); vI += __shfl_down(vI, o); vP += __shfl_down(vP, o);
  }
  if (tid) return;
  double Nd = (double)N;
  const float e32 = 1e-7f;
  const float c1 = 1.0f - e32;
  const float omc1 = 1.0f - c1;
  double lp1 = log((double)c1);
  double lp0 = log((double)e32);
  double l01 = log((double)omc1);
  double l00 = lp1;
  double L = vL + (double)AL(&stats[34]) * lp0 + (double)AL(&stats[35]) * l00;
  double res = -L / Nd;                                                    // bce_bg
  res += 1.0 - (2.0 * vI + 1.0) / (vP + (double)AL(&stats[8]) + 1.0);      // dice_bg
  unsigned ab2 = stats[33];
  for (int t = 1; t < 8; ++t) {
    if (ab2 >> t & 1u) {
      double a = (double)AL(&stats[56 + t]);
      double f = (double)AL(&stats[64 + t]);
      double n = (double)AL(&stats[8 + t]);
      double bce = -(a * lp1 + (n - a) * lp0 + (f - a) * l01 + (Nd - n - f + a) * l00) / Nd;
      double dice = 1.0 - (2.0 * a + 1.0) / (f + n + 1.0);
      res += bce + dice;
    }
  }
  int nu = 0;
  for (int t = 0; t < 8; ++t) nu += (AL(&stats[8 + t]) > 0);
  out[0] = (float)(res / ((double)nu + 1.0));
}

extern "C" void kernel_launch(void* const* d_in, const int* in_sizes, int n_in,
                              void* d_out, int out_size, void* d_ws, size_t ws_size,
                              hipStream_t stream) {
  const float* pred = (const float*)d_in[0];   // [B,8,512,512] f32
  const int* tgt = (const int*)d_in[1];        // [B,1,512,512] i32
  int N = in_sizes[1];                         // B*H*W
  char* ws = (char*)d_ws;
  int* parent = (int*)ws;
  unsigned* keys = (unsigned*)(ws + (size_t)N * 4);
  unsigned char* pk = (unsigned char*)(ws + (size_t)N * 8);
  unsigned* stats = (unsigned*)(ws + (size_t)N * 9);
  unsigned* ghist = stats + 8192;
  float* out = (float*)d_out;

  k_zero<<<88, 256, 0, stream>>>(stats);
  k_argmax<<<1024, 256, 0, stream>>>(pred, tgt, parent, pk, stats, N);
  k_merge<<<2048, 256, 0, stream>>>(pk, parent, N);
  k_flatten<<<2048, 256, 0, stream>>>(pk, parent, stats, N);
  k_ph_hist<<<1024, 256, 0, stream>>>(pk, parent, keys, stats, ghist, N);
  k_histp<<<1024, 256, 0, stream>>>(keys, pk, stats, ghist, N, 2);
  k_histp<<<1024, 256, 0, stream>>>(keys, pk, stats, ghist, N, 3);
  k_med<<<1024, 256, 0, stream>>>(keys, pk, stats, out, N);
}

// Round 5
// 140.374 us; speedup vs baseline: 3.6382x; 1.3696x over previous
//
#include <hip/hip_runtime.h>
#include <math.h>

// ConnectedLossV4, 8-node graph. Grid barriers = kernel boundaries (cg grid.sync
// ~55us/sync on MI355X: cross-XCD L2 WB/INV). Last-block folding uses RELAXED
// arrival counters: ACQ_REL agent-scope RMW emits buffer_wbl2/inv sc1 PER BLOCK
// (R4: k_flatten 59us @ 1.4% VALUBusy with 2048 acq_rel arrivals). Ordering is
// guaranteed by __syncthreads (compiler drains vmcnt(0) before s_barrier) and
// visibility by global atomics executing at the device coherence point.
//   1 k_zero     zero stats+ghist
//   2 k_argmax   argmax + bg-bce/dice continuous part + class/target counts
//   3 k_merge    4-connected union-find (min-root CAS), vectorized loads
//   4 k_flatten  read-only find -> parent[i]=root (race-free labels) + ncomp;
//                LAST BLOCK: scalars (prodf, pb/ab, ph0 anchor, s1, ranks)
//   5 k_ph_hist  placeholder keys (exact f32 op order) + anchored radix pass 1;
//                LAST BLOCK scans -> median bin
//   6 k_histp(2) early-exit stub unless window needed >11 bits
//   7 k_histp(3) early-exit stub (always resolved by pass 3)
//   8 k_med      median-match counts; LAST BLOCK -> closed-form bce+dice -> out
//
// ws layout (N = B*H*W = 1048576):
//   [0,4N) parent | [4N,8N) keys | [8N,9N) pk = cls|tgt<<3 | [9N,..) stats+ghist
// stats words: 0..7 cntClass, 8..15 cntTarget, 16..23 ncomp, 24..31 prodf bits,
//   32 pb, 33 ab, 34 n(c!=0,t=0), 35 n(c!=0,t!=0), 36 ph0 bits, 37 s1,
//   38 resolved, 40..47 median-offset prefix, 48..55 krem, 56..63 n11,
//   64..71 nfm, 76..80 arrival counters, 96.. dsl double[3][32].
//   ghist = stats + 8192 words, uint32[7][2048].

#define HWMASK (262144 - 1)
#define AL(p) __hip_atomic_load((p), __ATOMIC_RELAXED, __HIP_MEMORY_SCOPE_AGENT)
#define ARRIVE(p) __hip_atomic_fetch_add((p), 1u, __ATOMIC_RELAXED, __HIP_MEMORY_SCOPE_AGENT)

static __device__ __forceinline__ int ufind(int* p, int x) {
  while (true) {
    int px = p[x];
    if (px == x) return x;
    int g = p[px];
    if (g == px) return px;
    p[x] = g;  // path halving (benign race for merge-phase invariants)
    x = g;
  }
}

static __device__ __forceinline__ void unite(int* p, int a, int b) {
  while (true) {
    a = ufind(p, a); b = ufind(p, b);
    if (a == b) return;
    if (a < b) { int old = atomicCAS(&p[b], b, a); if (old == b) return; b = old; }
    else       { int old = atomicCAS(&p[a], a, b); if (old == a) return; a = old; }
  }
}

__global__ void k_zero(unsigned* __restrict__ stats) {
  int i = blockIdx.x * blockDim.x + threadIdx.x;
  if (i < 22528) stats[i] = 0u;   // 8192 stats + 14336 ghist
}

__global__ __launch_bounds__(256) void k_argmax(
    const float* __restrict__ pred, const int* __restrict__ tgt,
    int* __restrict__ parent, unsigned char* __restrict__ pk,
    unsigned* __restrict__ stats, int N) {
  __shared__ unsigned hc[8], ht[8], hA, hB;
  __shared__ double dred[12];
  int tid = threadIdx.x;
  if (tid < 8) { hc[tid] = 0; ht[tid] = 0; }
  if (tid == 0) { hA = 0; hB = 0; }
  __syncthreads();
  int n4 = N >> 2;
  int gsz = gridDim.x * blockDim.x;
  double aL = 0.0, aI = 0.0, aP = 0.0;
  unsigned nA = 0, nB = 0;
  for (int i4 = blockIdx.x * blockDim.x + tid; i4 < n4; i4 += gsz) {
    int i = i4 << 2;
    int b = i >> 18, hw = i & HWMASK;
    const float* pp = pred + ((size_t)b << 21) + hw;
    float4 v[8];
#pragma unroll
    for (int ch = 0; ch < 8; ++ch) v[ch] = *(const float4*)(pp + ((size_t)ch << 18));
    int4 tv = *(const int4*)(tgt + i);
    int tarr[4] = {tv.x & 7, tv.y & 7, tv.z & 7, tv.w & 7};
    unsigned char pkb[4];
#pragma unroll
    for (int j = 0; j < 4; ++j) {
      float p0 = ((const float*)&v[0])[j];
      float best = p0; int c = 0;
#pragma unroll
      for (int ch = 1; ch < 8; ++ch) {          // first-max == numpy argmax
        float x = ((const float*)&v[ch])[j];
        if (x > best) { best = x; c = ch; }
      }
      int t = tarr[j];
      pkb[j] = (unsigned char)(c | (t << 3));
      atomicAdd(&hc[c], 1u);
      atomicAdd(&ht[t], 1u);
      if (c == 0) {                             // continuous bg term
        float pc = fminf(fmaxf(p0, 1e-7f), 1.0f - 1e-7f);
        if (t == 0) { aL += (double)logf(pc); aI += (double)p0; }
        else        { aL += (double)logf(1.0f - pc); }
        aP += (double)p0;
      } else { if (t == 0) nA++; else nB++; }   // pv==0 -> constant log, count
    }
    *(int4*)(parent + i) = make_int4(i, i + 1, i + 2, i + 3);
    *(uchar4*)(pk + i) = make_uchar4(pkb[0], pkb[1], pkb[2], pkb[3]);
  }
  if (nA) atomicAdd(&hA, nA);
  if (nB) atomicAdd(&hB, nB);
#pragma unroll
  for (int o = 32; o > 0; o >>= 1) {
    aL += __shfl_down(aL, o); aI += __shfl_down(aI, o); aP += __shfl_down(aP, o);
  }
  int wid = tid >> 6, lane = tid & 63;
  if (lane == 0) { dred[wid] = aL; dred[4 + wid] = aI; dred[8 + wid] = aP; }
  __syncthreads();
  if (tid == 0) {
    double* dsl = (double*)(stats + 96);
    int s = blockIdx.x & 31;
    atomicAdd(&dsl[s],      dred[0] + dred[1] + dred[2] + dred[3]);
    atomicAdd(&dsl[32 + s], dred[4] + dred[5] + dred[6] + dred[7]);
    atomicAdd(&dsl[64 + s], dred[8] + dred[9] + dred[10] + dred[11]);
    if (hA) atomicAdd(&stats[34], hA);
    if (hB) atomicAdd(&stats[35], hB);
  }
  if (tid < 8) {
    if (hc[tid]) atomicAdd(&stats[tid], hc[tid]);
    if (ht[tid]) atomicAdd(&stats[8 + tid], ht[tid]);
  }
}

__global__ __launch_bounds__(256) void k_merge(
    const unsigned char* __restrict__ pk, int* __restrict__ parent, int N) {
  int n4 = N >> 2, gsz = gridDim.x * blockDim.x;
  for (int i4 = blockIdx.x * blockDim.x + threadIdx.x; i4 < n4; i4 += gsz) {
    int i = i4 << 2;
    int hw = i & HWMASK;
    uchar4 a = *(const uchar4*)(pk + i);
    unsigned char ca[4] = {(unsigned char)(a.x & 7), (unsigned char)(a.y & 7),
                           (unsigned char)(a.z & 7), (unsigned char)(a.w & 7)};
    // horizontal edges inside the quad
    if (ca[0] && ca[0] == ca[1]) unite(parent, i,     i + 1);
    if (ca[1] && ca[1] == ca[2]) unite(parent, i + 1, i + 2);
    if (ca[2] && ca[2] == ca[3]) unite(parent, i + 2, i + 3);
    if ((hw & 511) < 508) {                       // quad-boundary edge, same row
      unsigned char nx = pk[i + 4] & 7;
      if (ca[3] && ca[3] == nx) unite(parent, i + 3, i + 4);
    }
    if ((hw >> 9) < 511) {                        // vertical edges
      uchar4 d = *(const uchar4*)(pk + i + 512);
      unsigned char da[4] = {(unsigned char)(d.x & 7), (unsigned char)(d.y & 7),
                             (unsigned char)(d.z & 7), (unsigned char)(d.w & 7)};
#pragma unroll
      for (int j = 0; j < 4; ++j)
        if (ca[j] && ca[j] == da[j]) unite(parent, i + j, i + j + 512);
    }
  }
}

__global__ __launch_bounds__(256) void k_flatten(
    const unsigned char* __restrict__ pk, int* __restrict__ parent,
    unsigned* __restrict__ stats, int N) {
  __shared__ unsigned nc[8];
  __shared__ int lastF;
  int tid = threadIdx.x;
  if (tid < 8) nc[tid] = 0;
  __syncthreads();
  int n4 = N >> 2, gsz = gridDim.x * blockDim.x;
  for (int i4 = blockIdx.x * blockDim.x + tid; i4 < n4; i4 += gsz) {
    int i = i4 << 2;
    uchar4 a = *(const uchar4*)(pk + i);
    int4 p = *(const int4*)(parent + i);
    int pa[4] = {p.x, p.y, p.z, p.w};
    unsigned char ca[4] = {(unsigned char)(a.x & 7), (unsigned char)(a.y & 7),
                           (unsigned char)(a.z & 7), (unsigned char)(a.w & 7)};
#pragma unroll
    for (int j = 0; j < 4; ++j) {
      if (!ca[j]) continue;
      int x = pa[j];
      if (x == i + j) { atomicAdd(&nc[ca[j]], 1u); continue; }  // representative
      // READ-ONLY root chase: no halving stores here, so each parent slot has a
      // single writer (its owner) -> final parent[] is exactly the root label.
      while (true) { int nx = parent[x]; if (nx == x) break; x = nx; }
      pa[j] = x;
    }
    *(int4*)(parent + i) = make_int4(pa[0], pa[1], pa[2], pa[3]);
  }
  __syncthreads();
  if (tid < 8 && nc[tid]) atomicAdd(&stats[16 + tid], nc[tid]);
  __syncthreads();  // compiler drains vmcnt(0) before s_barrier -> atomics done
  if (tid == 0) lastF = (ARRIVE(&stats[76]) == gridDim.x - 1);
  __syncthreads();
  if (!lastF || tid != 0) return;
  // ---- scalars (single thread; ~100 ops) --------------------------------
  unsigned cntc[8], nco[8], cntt[8];
  for (int v = 0; v < 8; ++v) {
    cntc[v] = AL(&stats[v]); nco[v] = AL(&stats[16 + v]); cntt[v] = AL(&stats[8 + v]);
  }
  float prodf[8]; int last_i = 1; unsigned pb = 0;
  for (int v = 1; v < 8; ++v) {
    prodf[v] = 0.0f;
    if (cntc[v]) {
      prodf[v] = __fmul_rn((float)nco[v], (float)last_i);   // exact ref rounding
      pb |= 1u << v;
      last_i += (int)nco[v] + ((cntc[v] < (unsigned)N) ? 1 : 0);  // + has_bg
    }
    stats[24 + v] = __float_as_uint(prodf[v]);
  }
  float ph0 = 0.0f;   // background key (min key: rounding is monotone)
  for (int v = 1; v < 8; ++v) if (pb & (1u << v)) ph0 = __fadd_rn(ph0, prodf[v]);
  unsigned ab = 0;
  for (int t = 1; t < 8; ++t) {
    unsigned n = cntt[t];
    ((int*)stats)[48 + t] = n ? (int)((n - 1) >> 1) : -1;   // lower-median rank
    if (n) ab |= 1u << t;
  }
  stats[32] = pb; stats[33] = ab;
  unsigned pbits = __float_as_uint(ph0);
  stats[36] = pbits;
  // key-code window bound: codes in (ph0, ph0+2^20] <= 2^(43-e), e=exp(ph0)
  unsigned c;
  if (pbits == 0) c = 64u;
  else {
    int e = (int)(pbits >> 23) - 127;
    int sh = 43 - e;
    if (sh <= 0) c = 64u;
    else if (sh >= 31) c = 0x7FFFFFFFu;
    else c = (1u << sh) + 64u;
  }
  int bl = 32 - __clz((int)c);
  stats[37] = (bl > 11) ? (unsigned)(bl - 11) : 0u;   // s1
}

static __device__ void scan_select(unsigned* __restrict__ stats, unsigned* __restrict__ ghist,
                                   unsigned abm, int s_cur, unsigned* lh) {
  int tid = threadIdx.x;
  for (int t = 1; t < 8; ++t) {
    if (!(abm >> t & 1u)) continue;
    int k = ((int*)stats)[48 + t];
    unsigned* h = ghist + ((t - 1) << 11);
    int base = tid << 3;
    unsigned loc[8]; unsigned sm = 0;
#pragma unroll
    for (int j = 0; j < 8; ++j) { loc[j] = AL(&h[base + j]); sm += loc[j]; }
    lh[tid] = sm;
    __syncthreads();
    for (int o = 1; o < 256; o <<= 1) {   // inclusive Hillis-Steele
      unsigned v = (tid >= o) ? lh[tid - o] : 0u;
      __syncthreads();
      lh[tid] += v;
      __syncthreads();
    }
    unsigned incl = lh[tid], excl = incl - sm;
    if ((unsigned)k >= excl && (unsigned)k < incl) {   // unique owner
      unsigned cum = excl;
#pragma unroll
      for (int j = 0; j < 8; ++j) {
        unsigned cc = loc[j];
        if (cum + cc > (unsigned)k) {
          stats[40 + t] |= ((unsigned)(base + j)) << s_cur;
          ((int*)stats)[48 + t] = k - (int)cum;
          break;
        }
        cum += cc;
      }
    }
    __syncthreads();
  }
}

__global__ __launch_bounds__(256) void k_ph_hist(
    const unsigned char* __restrict__ pk, const int* __restrict__ parent,
    unsigned* __restrict__ keys, unsigned* __restrict__ stats,
    unsigned* __restrict__ ghist, int N) {
  __shared__ unsigned lh[14336];
  __shared__ float sprod[8];
  __shared__ unsigned sb[8];
  int tid = threadIdx.x;
  if (tid < 8) sprod[tid] = __uint_as_float(stats[24 + tid]);
  if (tid == 0) { sb[0] = stats[32]; sb[1] = stats[33]; sb[2] = stats[36]; sb[3] = stats[37]; }
  for (int j = tid; j < 14336; j += blockDim.x) lh[j] = 0u;
  __syncthreads();
  unsigned pb = sb[0], ab = sb[1], ph0 = sb[2];
  int s1 = (int)sb[3];
  int n4 = N >> 2, gsz = gridDim.x * blockDim.x;
  for (int i4 = blockIdx.x * blockDim.x + tid; i4 < n4; i4 += gsz) {
    int i = i4 << 2;
    int4 pr = *(const int4*)(parent + i);
    uchar4 pv = *(const uchar4*)(pk + i);
    int parr[4] = {pr.x, pr.y, pr.z, pr.w};
    unsigned char pa[4] = {pv.x, pv.y, pv.z, pv.w};
    unsigned ko[4];
#pragma unroll
    for (int j = 0; j < 4; ++j) {
      int c = pa[j] & 7, t = pa[j] >> 3;
      float lab = c ? (float)(parr[j] + 1) : 0.0f;   // < 2^24, exact
      float ph = 0.0f;
#pragma unroll
      for (int v = 1; v < 8; ++v) {                  // exact numpy op order
        if (pb & (1u << v)) {
          float term = sprod[v];
          if (c == v) term = __fadd_rn(lab, term);
          ph = __fadd_rn(ph, term);
        }
      }
      unsigned kb = __float_as_uint(ph);
      ko[j] = kb;
      if (t && (ab >> t & 1u)) {                     // radix pass 1, anchored
        unsigned off = kb - ph0;                     // >= 0 by monotonicity
        unsigned bin = off >> s1;
        if (bin > 2047u) bin = 2047u;                // belt-and-braces
        atomicAdd(&lh[((t - 1) << 11) | bin], 1u);
      }
    }
    *(uint4*)(keys + i) = make_uint4(ko[0], ko[1], ko[2], ko[3]);
  }
  __syncthreads();
  for (int j = tid; j < 14336; j += blockDim.x) {
    unsigned v = lh[j];
    if (v) atomicAdd(&ghist[j], v);
  }
  __syncthreads();
  if (tid == 0) sb[4] = (ARRIVE(&stats[77]) == gridDim.x - 1) ? 1u : 0u;
  __syncthreads();
  if (!sb[4]) return;
  scan_select(stats, ghist, ab, s1, lh);
  if (tid == 0) stats[38] = (s1 == 0) ? 1u : 0u;
  if (s1 > 0) for (int j = tid; j < 14336; j += blockDim.x) ghist[j] = 0u;
}

__global__ __launch_bounds__(256) void k_histp(
    const unsigned* __restrict__ keys, const unsigned char* __restrict__ pk,
    unsigned* __restrict__ stats, unsigned* __restrict__ ghist, int N, int pass) {
  __shared__ unsigned lh[14336];
  __shared__ unsigned sb[16];
  int tid = threadIdx.x;
  if (tid < 8) sb[8 + tid] = stats[40 + tid];
  if (tid == 0) { sb[0] = stats[38]; sb[1] = stats[33]; sb[2] = stats[36]; sb[3] = stats[37]; }
  __syncthreads();
  if (sb[0]) return;                       // already resolved -> stub
  unsigned ab = sb[1], ph0 = sb[2];
  int s1 = (int)sb[3];
  int sprev = s1 - 11 * (pass - 2); if (sprev < 0) sprev = 0;
  int scur  = s1 - 11 * (pass - 1); if (scur  < 0) scur  = 0;
  unsigned maskhi = 0xFFFFFFFFu << sprev;  // sprev >= 1 when unresolved
  for (int j = tid; j < 14336; j += blockDim.x) lh[j] = 0u;
  __syncthreads();
  int n4 = N >> 2, gsz = gridDim.x * blockDim.x;
  for (int i4 = blockIdx.x * blockDim.x + tid; i4 < n4; i4 += gsz) {
    int i = i4 << 2;
    uint4 kv = *(const uint4*)(keys + i);
    uchar4 pv = *(const uchar4*)(pk + i);
    unsigned karr[4] = {kv.x, kv.y, kv.z, kv.w};
    unsigned char pa[4] = {pv.x, pv.y, pv.z, pv.w};
#pragma unroll
    for (int j = 0; j < 4; ++j) {
      int t = pa[j] >> 3;
      if (t && (ab >> t & 1u)) {
        unsigned off = karr[j] - ph0;
        if (((off ^ sb[8 + t]) & maskhi) == 0u)
          atomicAdd(&lh[((t - 1) << 11) | ((off >> scur) & 2047u)], 1u);
      }
    }
  }
  __syncthreads();
  for (int j = tid; j < 14336; j += blockDim.x) {
    unsigned v = lh[j];
    if (v) atomicAdd(&ghist[j], v);
  }
  __syncthreads();
  if (tid == 0) sb[4] = (ARRIVE(&stats[76 + pass]) == gridDim.x - 1) ? 1u : 0u;
  __syncthreads();
  if (!sb[4]) return;
  scan_select(stats, ghist, ab, scur, lh);
  if (tid == 0) stats[38] = (scur == 0) ? 1u : 0u;
  if (scur > 0) for (int j = tid; j < 14336; j += blockDim.x) ghist[j] = 0u;
}

__global__ __launch_bounds__(256) void k_med(
    const unsigned* __restrict__ keys, const unsigned char* __restrict__ pk,
    unsigned* __restrict__ stats, float* __restrict__ out, int N) {
  __shared__ unsigned s11[8], sfm[8], smed[8], sab;
  __shared__ int lastF;
  int tid = threadIdx.x;
  if (tid < 8) { s11[tid] = 0; sfm[tid] = 0; smed[tid] = stats[36] + stats[40 + tid]; }
  if (tid == 0) sab = stats[33];
  __syncthreads();
  unsigned ab = sab;
  int n4 = N >> 2, gsz = gridDim.x * blockDim.x;
  for (int i4 = blockIdx.x * blockDim.x + tid; i4 < n4; i4 += gsz) {
    int i = i4 << 2;
    uint4 kv = *(const uint4*)(keys + i);
    uchar4 pv = *(const uchar4*)(pk + i);
    unsigned karr[4] = {kv.x, kv.y, kv.z, kv.w};
    unsigned char pa[4] = {pv.x, pv.y, pv.z, pv.w};
#pragma unroll
    for (int j = 0; j < 4; ++j) {
      unsigned kb = karr[j];
      int t = pa[j] >> 3;
#pragma unroll
      for (int tt = 1; tt < 8; ++tt) {
        if ((ab >> tt & 1u) && kb == smed[tt]) {
          atomicAdd(&sfm[tt], 1u);
          if (t == tt) atomicAdd(&s11[tt], 1u);
        }
      }
    }
  }
  __syncthreads();
  if (tid < 8) {
    if (sfm[tid]) atomicAdd(&stats[64 + tid], sfm[tid]);   // |full_med|
    if (s11[tid]) atomicAdd(&stats[56 + tid], s11[tid]);   // n11
  }
  __syncthreads();
  if (tid == 0) lastF = (ARRIVE(&stats[80]) == gridDim.x - 1);
  __syncthreads();
  if (!lastF || tid >= 64) return;
  // ---- finalize ----------------------------------------------------------
  const double* dsl = (const double*)(stats + 96);
  double vL = 0.0, vI = 0.0, vP = 0.0;
  if (tid < 32) { vL = dsl[tid]; vI = dsl[32 + tid]; vP = dsl[64 + tid]; }
#pragma unroll
  for (int o = 32; o > 0; o >>= 1) {
    vL += __shfl_down(vL, o); vI += __shfl_down(vI, o); vP += __shfl_down(vP, o);
  }
  if (tid) return;
  double Nd = (double)N;
  const float e32 = 1e-7f;
  const float c1 = 1.0f - e32;
  const float omc1 = 1.0f - c1;
  double lp1 = log((double)c1);
  double lp0 = log((double)e32);
  double l01 = log((double)omc1);
  double l00 = lp1;
  double L = vL + (double)AL(&stats[34]) * lp0 + (double)AL(&stats[35]) * l00;
  double res = -L / Nd;                                                    // bce_bg
  res += 1.0 - (2.0 * vI + 1.0) / (vP + (double)AL(&stats[8]) + 1.0);      // dice_bg
  unsigned ab2 = stats[33];
  for (int t = 1; t < 8; ++t) {
    if (ab2 >> t & 1u) {
      double a = (double)AL(&stats[56 + t]);
      double f = (double)AL(&stats[64 + t]);
      double n = (double)AL(&stats[8 + t]);
      double bce = -(a * lp1 + (n - a) * lp0 + (f - a) * l01 + (Nd - n - f + a) * l00) / Nd;
      double dice = 1.0 - (2.0 * a + 1.0) / (f + n + 1.0);
      res += bce + dice;
    }
  }
  int nu = 0;
  for (int t = 0; t < 8; ++t) nu += (AL(&stats[8 + t]) > 0);
  out[0] = (float)(res / ((double)nu + 1.0));
}

extern "C" void kernel_launch(void* const* d_in, const int* in_sizes, int n_in,
                              void* d_out, int out_size, void* d_ws, size_t ws_size,
                              hipStream_t stream) {
  const float* pred = (const float*)d_in[0];   // [B,8,512,512] f32
  const int* tgt = (const int*)d_in[1];        // [B,1,512,512] i32
  int N = in_sizes[1];                         // B*H*W
  char* ws = (char*)d_ws;
  int* parent = (int*)ws;
  unsigned* keys = (unsigned*)(ws + (size_t)N * 4);
  unsigned char* pk = (unsigned char*)(ws + (size_t)N * 8);
  unsigned* stats = (unsigned*)(ws + (size_t)N * 9);
  unsigned* ghist = stats + 8192;
  float* out = (float*)d_out;

  k_zero<<<88, 256, 0, stream>>>(stats);
  k_argmax<<<1024, 256, 0, stream>>>(pred, tgt, parent, pk, stats, N);
  k_merge<<<1024, 256, 0, stream>>>(pk, parent, N);
  k_flatten<<<1024, 256, 0, stream>>>(pk, parent, stats, N);
  k_ph_hist<<<1024, 256, 0, stream>>>(pk, parent, keys, stats, ghist, N);
  k_histp<<<1024, 256, 0, stream>>>(keys, pk, stats, ghist, N, 2);
  k_histp<<<1024, 256, 0, stream>>>(keys, pk, stats, ghist, N, 3);
  k_med<<<1024, 256, 0, stream>>>(keys, pk, stats, out, N);
}

// Round 6
// 125.630 us; speedup vs baseline: 4.0652x; 1.1174x over previous
//
#include <hip/hip_runtime.h>
#include <math.h>

// ConnectedLossV4, 7-node graph. Grid barriers = kernel boundaries (cg grid.sync
// ~55us/sync on MI355X: cross-XCD L2 WB/INV; ACQ_REL per-block arrivals cost the
// same way -> all arrivals RELAXED; ordering via __syncthreads vmcnt drain,
// visibility via coherence-point atomics).
//   1 k_zero      zero stats+ghist
//   2 k_argmax    argmax + bg-bce/dice continuous part + class/target counts
//   3 k_merge     4-connected union-find (min-root CAS), vectorized loads
//   4 k_flatten   read-only find -> parent[i]=root + ncomp; LAST BLOCK: scalars
//   5 k_ph_hist   placeholder keys (exact f32 op order) + anchored 8-bit radix
//                 pass 1 into per-(blockIdx&7) ghist REPLICA (R5: one shared
//                 ghist = ~1024-way hot-word atomic contention, 43us);
//                 LAST BLOCK sums replicas + scans -> median bin
//   6 k_histp_all fallback radix passes 2..4 in ONE kernel with internal
//                 arrive+spin barrier (rare path; common path = early-exit stub)
//   7 k_med       median-match counts; LAST BLOCK -> closed-form bce+dice -> out
//
// ws layout (N = B*H*W = 1048576):
//   [0,4N) parent | [4N,8N) keys | [8N,9N) pk = cls|tgt<<3 | [9N,..) stats+ghist
// stats words: 0..7 cntClass, 8..15 cntTarget, 16..23 ncomp, 24..31 prodf bits,
//   32 pb, 33 ab, 34 n(c!=0,t=0), 35 n(c!=0,t!=0), 36 ph0 bits, 37 s1,
//   38 resolved-after-pass1, 39 pass-progress flag, 40..47 median-offset prefix,
//   48..55 krem, 56..63 n11, 64..71 nfm, 76..80 arrival counters (flatten=76,
//   ph_hist=77, histp pass p=76+p), 84 med arrival, 96..287 dsl double[3][32].
//   ghist = stats + 8192 words: 8 replicas x 7 targets x 256 bins = 14336 words.

#define HWMASK (262144 - 1)
#define AL(p) __hip_atomic_load((p), __ATOMIC_RELAXED, __HIP_MEMORY_SCOPE_AGENT)
#define ARRIVE(p) __hip_atomic_fetch_add((p), 1u, __ATOMIC_RELAXED, __HIP_MEMORY_SCOPE_AGENT)

static __device__ __forceinline__ int ufind(int* p, int x) {
  while (true) {
    int px = p[x];
    if (px == x) return x;
    int g = p[px];
    if (g == px) return px;
    p[x] = g;  // path halving (benign race for merge-phase invariants)
    x = g;
  }
}

static __device__ __forceinline__ void unite(int* p, int a, int b) {
  while (true) {
    a = ufind(p, a); b = ufind(p, b);
    if (a == b) return;
    if (a < b) { int old = atomicCAS(&p[b], b, a); if (old == b) return; b = old; }
    else       { int old = atomicCAS(&p[a], a, b); if (old == a) return; a = old; }
  }
}

__global__ void k_zero(unsigned* __restrict__ stats) {
  int i = blockIdx.x * blockDim.x + threadIdx.x;
  if (i < 22528) stats[i] = 0u;   // 8192 stats + 14336 ghist
}

__global__ __launch_bounds__(256) void k_argmax(
    const float* __restrict__ pred, const int* __restrict__ tgt,
    int* __restrict__ parent, unsigned char* __restrict__ pk,
    unsigned* __restrict__ stats, int N) {
  __shared__ unsigned hc[8], ht[8], hA, hB;
  __shared__ double dred[12];
  int tid = threadIdx.x;
  if (tid < 8) { hc[tid] = 0; ht[tid] = 0; }
  if (tid == 0) { hA = 0; hB = 0; }
  __syncthreads();
  int n4 = N >> 2;
  int gsz = gridDim.x * blockDim.x;
  double aL = 0.0, aI = 0.0, aP = 0.0;
  unsigned nA = 0, nB = 0;
  for (int i4 = blockIdx.x * blockDim.x + tid; i4 < n4; i4 += gsz) {
    int i = i4 << 2;
    int b = i >> 18, hw = i & HWMASK;
    const float* pp = pred + ((size_t)b << 21) + hw;
    float4 v[8];
#pragma unroll
    for (int ch = 0; ch < 8; ++ch) v[ch] = *(const float4*)(pp + ((size_t)ch << 18));
    int4 tv = *(const int4*)(tgt + i);
    int tarr[4] = {tv.x & 7, tv.y & 7, tv.z & 7, tv.w & 7};
    unsigned char pkb[4];
#pragma unroll
    for (int j = 0; j < 4; ++j) {
      float p0 = ((const float*)&v[0])[j];
      float best = p0; int c = 0;
#pragma unroll
      for (int ch = 1; ch < 8; ++ch) {          // first-max == numpy argmax
        float x = ((const float*)&v[ch])[j];
        if (x > best) { best = x; c = ch; }
      }
      int t = tarr[j];
      pkb[j] = (unsigned char)(c | (t << 3));
      atomicAdd(&hc[c], 1u);
      atomicAdd(&ht[t], 1u);
      if (c == 0) {                             // continuous bg term
        float pc = fminf(fmaxf(p0, 1e-7f), 1.0f - 1e-7f);
        if (t == 0) { aL += (double)logf(pc); aI += (double)p0; }
        else        { aL += (double)logf(1.0f - pc); }
        aP += (double)p0;
      } else { if (t == 0) nA++; else nB++; }   // pv==0 -> constant log, count
    }
    *(int4*)(parent + i) = make_int4(i, i + 1, i + 2, i + 3);
    *(uchar4*)(pk + i) = make_uchar4(pkb[0], pkb[1], pkb[2], pkb[3]);
  }
  if (nA) atomicAdd(&hA, nA);
  if (nB) atomicAdd(&hB, nB);
#pragma unroll
  for (int o = 32; o > 0; o >>= 1) {
    aL += __shfl_down(aL, o); aI += __shfl_down(aI, o); aP += __shfl_down(aP, o);
  }
  int wid = tid >> 6, lane = tid & 63;
  if (lane == 0) { dred[wid] = aL; dred[4 + wid] = aI; dred[8 + wid] = aP; }
  __syncthreads();
  if (tid == 0) {
    double* dsl = (double*)(stats + 96);
    int s = blockIdx.x & 31;
    atomicAdd(&dsl[s],      dred[0] + dred[1] + dred[2] + dred[3]);
    atomicAdd(&dsl[32 + s], dred[4] + dred[5] + dred[6] + dred[7]);
    atomicAdd(&dsl[64 + s], dred[8] + dred[9] + dred[10] + dred[11]);
    if (hA) atomicAdd(&stats[34], hA);
    if (hB) atomicAdd(&stats[35], hB);
  }
  if (tid < 8) {
    if (hc[tid]) atomicAdd(&stats[tid], hc[tid]);
    if (ht[tid]) atomicAdd(&stats[8 + tid], ht[tid]);
  }
}

__global__ __launch_bounds__(256) void k_merge(
    const unsigned char* __restrict__ pk, int* __restrict__ parent, int N) {
  int n4 = N >> 2, gsz = gridDim.x * blockDim.x;
  for (int i4 = blockIdx.x * blockDim.x + threadIdx.x; i4 < n4; i4 += gsz) {
    int i = i4 << 2;
    int hw = i & HWMASK;
    uchar4 a = *(const uchar4*)(pk + i);
    unsigned char ca[4] = {(unsigned char)(a.x & 7), (unsigned char)(a.y & 7),
                           (unsigned char)(a.z & 7), (unsigned char)(a.w & 7)};
    // horizontal edges inside the quad
    if (ca[0] && ca[0] == ca[1]) unite(parent, i,     i + 1);
    if (ca[1] && ca[1] == ca[2]) unite(parent, i + 1, i + 2);
    if (ca[2] && ca[2] == ca[3]) unite(parent, i + 2, i + 3);
    if ((hw & 511) < 508) {                       // quad-boundary edge, same row
      unsigned char nx = pk[i + 4] & 7;
      if (ca[3] && ca[3] == nx) unite(parent, i + 3, i + 4);
    }
    if ((hw >> 9) < 511) {                        // vertical edges
      uchar4 d = *(const uchar4*)(pk + i + 512);
      unsigned char da[4] = {(unsigned char)(d.x & 7), (unsigned char)(d.y & 7),
                             (unsigned char)(d.z & 7), (unsigned char)(d.w & 7)};
#pragma unroll
      for (int j = 0; j < 4; ++j)
        if (ca[j] && ca[j] == da[j]) unite(parent, i + j, i + j + 512);
    }
  }
}

__global__ __launch_bounds__(256) void k_flatten(
    const unsigned char* __restrict__ pk, int* __restrict__ parent,
    unsigned* __restrict__ stats, int N) {
  __shared__ unsigned nc[8];
  __shared__ int lastF;
  int tid = threadIdx.x;
  if (tid < 8) nc[tid] = 0;
  __syncthreads();
  int n4 = N >> 2, gsz = gridDim.x * blockDim.x;
  for (int i4 = blockIdx.x * blockDim.x + tid; i4 < n4; i4 += gsz) {
    int i = i4 << 2;
    uchar4 a = *(const uchar4*)(pk + i);
    int4 p = *(const int4*)(parent + i);
    int pa[4] = {p.x, p.y, p.z, p.w};
    unsigned char ca[4] = {(unsigned char)(a.x & 7), (unsigned char)(a.y & 7),
                           (unsigned char)(a.z & 7), (unsigned char)(a.w & 7)};
#pragma unroll
    for (int j = 0; j < 4; ++j) {
      if (!ca[j]) continue;
      int x = pa[j];
      if (x == i + j) { atomicAdd(&nc[ca[j]], 1u); continue; }  // representative
      // READ-ONLY root chase: no halving stores here, so each parent slot has a
      // single writer (its owner) -> final parent[] is exactly the root label.
      while (true) { int nx = parent[x]; if (nx == x) break; x = nx; }
      pa[j] = x;
    }
    *(int4*)(parent + i) = make_int4(pa[0], pa[1], pa[2], pa[3]);
  }
  __syncthreads();
  if (tid < 8 && nc[tid]) atomicAdd(&stats[16 + tid], nc[tid]);
  __syncthreads();  // compiler drains vmcnt(0) before s_barrier -> atomics done
  if (tid == 0) lastF = (ARRIVE(&stats[76]) == gridDim.x - 1);
  __syncthreads();
  if (!lastF || tid != 0) return;
  // ---- scalars (single thread; ~100 ops) --------------------------------
  unsigned cntc[8], nco[8], cntt[8];
  for (int v = 0; v < 8; ++v) {
    cntc[v] = AL(&stats[v]); nco[v] = AL(&stats[16 + v]); cntt[v] = AL(&stats[8 + v]);
  }
  float prodf[8]; int last_i = 1; unsigned pb = 0;
  for (int v = 1; v < 8; ++v) {
    prodf[v] = 0.0f;
    if (cntc[v]) {
      prodf[v] = __fmul_rn((float)nco[v], (float)last_i);   // exact ref rounding
      pb |= 1u << v;
      last_i += (int)nco[v] + ((cntc[v] < (unsigned)N) ? 1 : 0);  // + has_bg
    }
    stats[24 + v] = __float_as_uint(prodf[v]);
  }
  float ph0 = 0.0f;   // background key (min key: rounding is monotone)
  for (int v = 1; v < 8; ++v) if (pb & (1u << v)) ph0 = __fadd_rn(ph0, prodf[v]);
  unsigned ab = 0;
  for (int t = 1; t < 8; ++t) {
    unsigned n = cntt[t];
    ((int*)stats)[48 + t] = n ? (int)((n - 1) >> 1) : -1;   // lower-median rank
    if (n) ab |= 1u << t;
  }
  stats[32] = pb; stats[33] = ab;
  unsigned pbits = __float_as_uint(ph0);
  stats[36] = pbits;
  // key-code window bound: codes in (ph0, ph0+2^20] <= 2^(43-e), e=exp(ph0)
  unsigned c;
  if (pbits == 0) c = 64u;
  else {
    int e = (int)(pbits >> 23) - 127;
    int sh = 43 - e;
    if (sh <= 0) c = 64u;
    else if (sh >= 31) c = 0x7FFFFFFFu;
    else c = (1u << sh) + 64u;
  }
  int bl = 32 - __clz((int)c);
  stats[37] = (bl > 8) ? (unsigned)(bl - 8) : 0u;   // s1 for 8-bit digits
}

// Sum 8 ghist replicas, scan 256 bins, pick the bin holding rank krem[t].
// Writes via coherence-point atomics (rare-path same-kernel visibility).
static __device__ void scan_select(unsigned* __restrict__ stats,
                                   const unsigned* __restrict__ ghist,
                                   unsigned abm, int s_cur, unsigned* lh) {
  int tid = threadIdx.x;
  for (int t = 1; t < 8; ++t) {
    if (!(abm >> t & 1u)) continue;
    int k = (int)AL(&stats[48 + t]);
    unsigned cnt = 0;
#pragma unroll
    for (int r = 0; r < 8; ++r)
      cnt += AL(&ghist[r * 1792 + ((t - 1) << 8) + tid]);
    lh[tid] = cnt;
    __syncthreads();
    for (int o = 1; o < 256; o <<= 1) {   // inclusive Hillis-Steele
      unsigned v = (tid >= o) ? lh[tid - o] : 0u;
      __syncthreads();
      lh[tid] += v;
      __syncthreads();
    }
    unsigned incl = lh[tid], excl = incl - cnt;
    if ((unsigned)k >= excl && (unsigned)k < incl) {   // unique owner
      atomicOr(&stats[40 + t], ((unsigned)tid) << s_cur);
      __hip_atomic_store(&stats[48 + t], (unsigned)(k - (int)excl),
                         __ATOMIC_RELAXED, __HIP_MEMORY_SCOPE_AGENT);
    }
    __syncthreads();
  }
}

__global__ __launch_bounds__(256) void k_ph_hist(
    const unsigned char* __restrict__ pk, const int* __restrict__ parent,
    unsigned* __restrict__ keys, unsigned* __restrict__ stats,
    unsigned* __restrict__ ghist, int N) {
  __shared__ unsigned lh[1792];     // 7 targets x 256 bins
  __shared__ float sprod[8];
  __shared__ unsigned sb[8];
  int tid = threadIdx.x;
  if (tid < 8) sprod[tid] = __uint_as_float(stats[24 + tid]);
  if (tid == 0) { sb[0] = stats[32]; sb[1] = stats[33]; sb[2] = stats[36]; sb[3] = stats[37]; }
  for (int j = tid; j < 1792; j += blockDim.x) lh[j] = 0u;
  __syncthreads();
  unsigned pb = sb[0], ab = sb[1], ph0 = sb[2];
  int s1 = (int)sb[3];
  unsigned rep = (blockIdx.x & 7) * 1792u;   // ghist replica for this block
  int n4 = N >> 2, gsz = gridDim.x * blockDim.x;
  for (int i4 = blockIdx.x * blockDim.x + tid; i4 < n4; i4 += gsz) {
    int i = i4 << 2;
    int4 pr = *(const int4*)(parent + i);
    uchar4 pv = *(const uchar4*)(pk + i);
    int parr[4] = {pr.x, pr.y, pr.z, pr.w};
    unsigned char pa[4] = {pv.x, pv.y, pv.z, pv.w};
    unsigned ko[4];
#pragma unroll
    for (int j = 0; j < 4; ++j) {
      int c = pa[j] & 7, t = pa[j] >> 3;
      float lab = c ? (float)(parr[j] + 1) : 0.0f;   // < 2^24, exact
      float ph = 0.0f;
#pragma unroll
      for (int v = 1; v < 8; ++v) {                  // exact numpy op order
        if (pb & (1u << v)) {
          float term = sprod[v];
          if (c == v) term = __fadd_rn(lab, term);
          ph = __fadd_rn(ph, term);
        }
      }
      unsigned kb = __float_as_uint(ph);
      ko[j] = kb;
      if (t && (ab >> t & 1u)) {                     // radix pass 1, anchored
        unsigned off = kb - ph0;                     // >= 0 by monotonicity
        unsigned bin = off >> s1;
        if (bin > 255u) bin = 255u;                  // belt-and-braces
        atomicAdd(&lh[((t - 1) << 8) | bin], 1u);
      }
    }
    *(uint4*)(keys + i) = make_uint4(ko[0], ko[1], ko[2], ko[3]);
  }
  __syncthreads();
  for (int j = tid; j < 1792; j += blockDim.x) {
    unsigned v = lh[j];
    if (v) atomicAdd(&ghist[rep + j], v);
  }
  __syncthreads();
  if (tid == 0) sb[4] = (ARRIVE(&stats[77]) == gridDim.x - 1) ? 1u : 0u;
  __syncthreads();
  if (!sb[4]) return;
  scan_select(stats, ghist, ab, s1, lh);
  if (tid == 0) stats[38] = (s1 == 0) ? 1u : 0u;
  if (s1 > 0) for (int j = tid; j < 14336; j += blockDim.x) ghist[j] = 0u;
}

// Fallback radix passes 2..4 (8-bit digits). Early-exits when pass 1 resolved
// (common). Rare path: internal arrive+spin grid barrier -- co-residency holds
// (512 blocks, 7KB LDS, <=64 VGPR -> >=4 blocks/CU capacity).
__global__ __launch_bounds__(256) void k_histp_all(
    const unsigned* __restrict__ keys, const unsigned char* __restrict__ pk,
    unsigned* __restrict__ stats, unsigned* __restrict__ ghist, int N) {
  __shared__ unsigned lh[1792];
  __shared__ unsigned sb[20];
  int tid = threadIdx.x;
  if (tid == 0) {
    sb[0] = stats[38]; sb[1] = stats[33]; sb[2] = stats[36]; sb[3] = stats[37];
  }
  __syncthreads();
  if (sb[0]) return;                 // resolved after pass 1 -> stub
  unsigned ab = sb[1], ph0 = sb[2];
  int s1 = (int)sb[3];
  unsigned rep = (blockIdx.x & 7) * 1792u;
  int n4 = N >> 2, gsz = gridDim.x * blockDim.x;
  for (int pass = 2; pass <= 4; ++pass) {
    int sprev = s1 - 8 * (pass - 2); if (sprev < 0) sprev = 0;
    int scur  = s1 - 8 * (pass - 1); if (scur  < 0) scur  = 0;
    unsigned maskhi = 0xFFFFFFFFu << sprev;
    if (tid < 8) sb[8 + tid] = AL(&stats[40 + tid]);   // current prefixes
    for (int j = tid; j < 1792; j += blockDim.x) lh[j] = 0u;
    __syncthreads();
    for (int i4 = blockIdx.x * blockDim.x + tid; i4 < n4; i4 += gsz) {
      int i = i4 << 2;
      uint4 kv = *(const uint4*)(keys + i);
      uchar4 pv = *(const uchar4*)(pk + i);
      unsigned karr[4] = {kv.x, kv.y, kv.z, kv.w};
      unsigned char pa[4] = {pv.x, pv.y, pv.z, pv.w};
#pragma unroll
      for (int j = 0; j < 4; ++j) {
        int t = pa[j] >> 3;
        if (t && (ab >> t & 1u)) {
          unsigned off = karr[j] - ph0;
          if (((off ^ sb[8 + t]) & maskhi) == 0u)
            atomicAdd(&lh[((t - 1) << 8) | ((off >> scur) & 255u)], 1u);
        }
      }
    }
    __syncthreads();
    for (int j = tid; j < 1792; j += blockDim.x) {
      unsigned v = lh[j];
      if (v) atomicAdd(&ghist[rep + j], v);
    }
    __syncthreads();
    if (tid == 0) sb[16] = (ARRIVE(&stats[76 + pass]) == gridDim.x - 1) ? 1u : 0u;
    __syncthreads();
    if (sb[16]) {
      scan_select(stats, ghist, ab, scur, lh);
      if (scur > 0)
        for (int j = tid; j < 14336; j += blockDim.x) ghist[j] = 0u;
      __syncthreads();
      if (tid == 0)   // release: flushes cleared ghist + scan results to LLC
        __hip_atomic_store(&stats[39], (unsigned)pass, __ATOMIC_RELEASE,
                           __HIP_MEMORY_SCOPE_AGENT);
    } else {
      if (tid == 0) {
        while (__hip_atomic_load(&stats[39], __ATOMIC_ACQUIRE,
                                 __HIP_MEMORY_SCOPE_AGENT) < (unsigned)pass)
          __builtin_amdgcn_s_sleep(8);
      }
      __syncthreads();
    }
    if (scur == 0) break;   // uniform across grid
  }
}

__global__ __launch_bounds__(256) void k_med(
    const unsigned* __restrict__ keys, const unsigned char* __restrict__ pk,
    unsigned* __restrict__ stats, float* __restrict__ out, int N) {
  __shared__ unsigned s11[8], sfm[8], smed[8], sab;
  __shared__ int lastF;
  int tid = threadIdx.x;
  if (tid < 8) { s11[tid] = 0; sfm[tid] = 0; smed[tid] = stats[36] + stats[40 + tid]; }
  if (tid == 0) sab = stats[33];
  __syncthreads();
  unsigned ab = sab;
  int n4 = N >> 2, gsz = gridDim.x * blockDim.x;
  for (int i4 = blockIdx.x * blockDim.x + tid; i4 < n4; i4 += gsz) {
    int i = i4 << 2;
    uint4 kv = *(const uint4*)(keys + i);
    uchar4 pv = *(const uchar4*)(pk + i);
    unsigned karr[4] = {kv.x, kv.y, kv.z, kv.w};
    unsigned char pa[4] = {pv.x, pv.y, pv.z, pv.w};
#pragma unroll
    for (int j = 0; j < 4; ++j) {
      unsigned kb = karr[j];
      int t = pa[j] >> 3;
#pragma unroll
      for (int tt = 1; tt < 8; ++tt) {
        if ((ab >> tt & 1u) && kb == smed[tt]) {
          atomicAdd(&sfm[tt], 1u);
          if (t == tt) atomicAdd(&s11[tt], 1u);
        }
      }
    }
  }
  __syncthreads();
  if (tid < 8) {
    if (sfm[tid]) atomicAdd(&stats[64 + tid], sfm[tid]);   // |full_med|
    if (s11[tid]) atomicAdd(&stats[56 + tid], s11[tid]);   // n11
  }
  __syncthreads();
  if (tid == 0) lastF = (ARRIVE(&stats[84]) == gridDim.x - 1);
  __syncthreads();
  if (!lastF || tid >= 64) return;
  // ---- finalize ----------------------------------------------------------
  const double* dsl = (const double*)(stats + 96);
  double vL = 0.0, vI = 0.0, vP = 0.0;
  if (tid < 32) { vL = dsl[tid]; vI = dsl[32 + tid]; vP = dsl[64 + tid]; }
#pragma unroll
  for (int o = 32; o > 0; o >>= 1) {
    vL += __shfl_down(vL, o); vI += __shfl_down(vI, o); vP += __shfl_down(vP, o);
  }
  if (tid) return;
  double Nd = (double)N;
  const float e32 = 1e-7f;
  const float c1 = 1.0f - e32;
  const float omc1 = 1.0f - c1;
  double lp1 = log((double)c1);
  double lp0 = log((double)e32);
  double l01 = log((double)omc1);
  double l00 = lp1;
  double L = vL + (double)AL(&stats[34]) * lp0 + (double)AL(&stats[35]) * l00;
  double res = -L / Nd;                                                    // bce_bg
  res += 1.0 - (2.0 * vI + 1.0) / (vP + (double)AL(&stats[8]) + 1.0);      // dice_bg
  unsigned ab2 = stats[33];
  for (int t = 1; t < 8; ++t) {
    if (ab2 >> t & 1u) {
      double a = (double)AL(&stats[56 + t]);
      double f = (double)AL(&stats[64 + t]);
      double n = (double)AL(&stats[8 + t]);
      double bce = -(a * lp1 + (n - a) * lp0 + (f - a) * l01 + (Nd - n - f + a) * l00) / Nd;
      double dice = 1.0 - (2.0 * a + 1.0) / (f + n + 1.0);
      res += bce + dice;
    }
  }
  int nu = 0;
  for (int t = 0; t < 8; ++t) nu += (AL(&stats[8 + t]) > 0);
  out[0] = (float)(res / ((double)nu + 1.0));
}

extern "C" void kernel_launch(void* const* d_in, const int* in_sizes, int n_in,
                              void* d_out, int out_size, void* d_ws, size_t ws_size,
                              hipStream_t stream) {
  const float* pred = (const float*)d_in[0];   // [B,8,512,512] f32
  const int* tgt = (const int*)d_in[1];        // [B,1,512,512] i32
  int N = in_sizes[1];                         // B*H*W
  char* ws = (char*)d_ws;
  int* parent = (int*)ws;
  unsigned* keys = (unsigned*)(ws + (size_t)N * 4);
  unsigned char* pk = (unsigned char*)(ws + (size_t)N * 8);
  unsigned* stats = (unsigned*)(ws + (size_t)N * 9);
  unsigned* ghist = stats + 8192;
  float* out = (float*)d_out;

  k_zero<<<88, 256, 0, stream>>>(stats);
  k_argmax<<<1024, 256, 0, stream>>>(pred, tgt, parent, pk, stats, N);
  k_merge<<<1024, 256, 0, stream>>>(pk, parent, N);
  k_flatten<<<1024, 256, 0, stream>>>(pk, parent, stats, N);
  k_ph_hist<<<512, 256, 0, stream>>>(pk, parent, keys, stats, ghist, N);
  k_histp_all<<<512, 256, 0, stream>>>(keys, pk, stats, ghist, N);
  k_med<<<1024, 256, 0, stream>>>(keys, pk, stats, out, N);
}

// Round 9
// 124.219 us; speedup vs baseline: 4.1113x; 1.0114x over previous
//
#include <hip/hip_runtime.h>
#include <math.h>

// ConnectedLossV4, 3-node graph. R6: per-node boundary cost (~8-11us) dominated
// (7 nodes, ~50us work, 125us total). Fused to 3 kernels; arrive+spin grid
// barriers only where co-residency is provable (__launch_bounds__(256,2) =>
// >=2 blocks/CU => 512 blocks co-resident). Cross-block data inside a fused
// kernel must use agent-scope atomic ld/st (LLC coherence point) -- R7 bug #2:
// plain path-halving stores sat dirty in per-XCD L2 and could write back AFTER
// flatten's root stores (arbitrary flush order across XCDs) -> halving stores
// are now AS (relaxed atomic, straight to LLC, drained by __syncthreads before
// the barrier). R7 bug #1: k_uf got nbam=512 but 1024 partials exist -> half
// the counts were dropped. Fixed: nbam=1024 everywhere.
//   1 k_argmax  block0 zeros stats+ghist; argmax + bg-bce/dice continuous part;
//               per-block partial counts/doubles via PLAIN stores (no atomics
//               -> nothing needs pre-zeroing); parent/pk init.
//   2 k_uf      merge (CAS union-find, atomic halving) -> arrive+spin barrier
//               -> flatten (read-only chase via atomic loads; single-writer
//               root stores) -> arrive -> last block reduces partials + scalars.
//   3 k_phase2  placeholder keys in REGISTERS (2 quads/thread), anchored 8-bit
//               radix pass 1 into per-(blockIdx&7) ghist replica -> arrive ->
//               last block scans -> release flag -> spin -> [rare fallback
//               passes] -> median-match counts from registers -> arrive ->
//               last block closed-form bce+dice -> out.
//
// ws layout (N = B*H*W = 1048576):
//   [0,4N) parent | [4N,5N) pk = cls|tgt<<3 | [5N,..) stats/ghist/partials
// stats words: 8..15 cntTarget totals, 16..23 ncomp, 24..31 prodf bits,
//   32 pb, 33 ab, 34 nA, 35 nB, 36 ph0 bits, 37 s1, 38 resolved, 39 radix
//   progress flag, 40..47 median-offset prefix, 48..55 krem, 56..63 n11,
//   64..71 nfm, arrivals: 76 merge, 85 flatten, 77 hist1, 78/79/80 passes,
//   84 med; 90 merge flag.
//   ghist = stats+8192 (8 replicas x 7 x 256 = 14336 words)
//   pcnt  = stats+22528 (1024 blocks x 20 words: cls[8], tgt[8], nA, nB, pad)
//   pdbl  = (double*)(stats+43008) (1024 x 3 doubles)

#define HWMASK (262144 - 1)
#define AL(p) __hip_atomic_load((p), __ATOMIC_RELAXED, __HIP_MEMORY_SCOPE_AGENT)
#define AS(p, v) __hip_atomic_store((p), (v), __ATOMIC_RELAXED, __HIP_MEMORY_SCOPE_AGENT)
#define REL(p, v) __hip_atomic_store((p), (v), __ATOMIC_RELEASE, __HIP_MEMORY_SCOPE_AGENT)
#define ARRIVE(p) __hip_atomic_fetch_add((p), 1u, __ATOMIC_RELAXED, __HIP_MEMORY_SCOPE_AGENT)

// Merge-phase find: plain reads are fine (CAS re-verifies against LLC truth),
// but the halving store MUST be atomic: a plain store can sit dirty in this
// XCD's L2 and write back over flatten's root store after the barrier.
static __device__ __forceinline__ int ufind(int* p, int x) {
  while (true) {
    int px = p[x];
    if (px == x) return x;
    int g = p[px];
    if (g == px) return px;
    AS(&p[x], g);  // path halving -> LLC (g is an ancestor: benign race)
    x = g;
  }
}

static __device__ __forceinline__ void unite(int* p, int a, int b) {
  while (true) {
    a = ufind(p, a); b = ufind(p, b);
    if (a == b) return;
    if (a < b) { int old = atomicCAS(&p[b], b, a); if (old == b) return; b = old; }
    else       { int old = atomicCAS(&p[a], a, b); if (old == a) return; a = old; }
  }
}

__global__ __launch_bounds__(256) void k_argmax(
    const float* __restrict__ pred, const int* __restrict__ tgt,
    int* __restrict__ parent, unsigned char* __restrict__ pk,
    unsigned* __restrict__ stats, unsigned* __restrict__ pcnt,
    double* __restrict__ pdbl, int N) {
  __shared__ unsigned hc[32], ht[32], hA, hB;   // per-wave banks (4 waves x 8)
  __shared__ double dred[12];
  int tid = threadIdx.x, bid = blockIdx.x;
  if (bid == 0) {     // zero stats+ghist; no other block touches them here
    uint4* z = (uint4*)stats;
    for (int j = tid; j < 5632; j += 256) z[j] = make_uint4(0u, 0u, 0u, 0u);
  }
  if (tid < 32) { hc[tid] = 0; ht[tid] = 0; }
  if (tid == 0) { hA = 0; hB = 0; }
  __syncthreads();
  int wb = (tid >> 6) << 3;     // wave bank base
  int n4 = N >> 2, gsz = gridDim.x * blockDim.x;
  double aL = 0.0, aI = 0.0, aP = 0.0;
  unsigned nA = 0, nB = 0;
  for (int i4 = bid * blockDim.x + tid; i4 < n4; i4 += gsz) {
    int i = i4 << 2;
    int b = i >> 18, hw = i & HWMASK;
    const float* pp = pred + ((size_t)b << 21) + hw;
    float4 v[8];
#pragma unroll
    for (int ch = 0; ch < 8; ++ch) v[ch] = *(const float4*)(pp + ((size_t)ch << 18));
    int4 tv = *(const int4*)(tgt + i);
    int tarr[4] = {tv.x & 7, tv.y & 7, tv.z & 7, tv.w & 7};
    unsigned char pkb[4];
#pragma unroll
    for (int j = 0; j < 4; ++j) {
      float p0 = ((const float*)&v[0])[j];
      float best = p0; int c = 0;
#pragma unroll
      for (int ch = 1; ch < 8; ++ch) {          // first-max == numpy argmax
        float x = ((const float*)&v[ch])[j];
        if (x > best) { best = x; c = ch; }
      }
      int t = tarr[j];
      pkb[j] = (unsigned char)(c | (t << 3));
      atomicAdd(&hc[wb + c], 1u);
      atomicAdd(&ht[wb + t], 1u);
      if (c == 0) {                             // continuous bg term
        float pc = fminf(fmaxf(p0, 1e-7f), 1.0f - 1e-7f);
        if (t == 0) { aL += (double)logf(pc); aI += (double)p0; }
        else        { aL += (double)logf(1.0f - pc); }
        aP += (double)p0;
      } else { if (t == 0) nA++; else nB++; }   // pv==0 -> constant log, count
    }
    *(int4*)(parent + i) = make_int4(i, i + 1, i + 2, i + 3);
    *(uchar4*)(pk + i) = make_uchar4(pkb[0], pkb[1], pkb[2], pkb[3]);
  }
  if (nA) atomicAdd(&hA, nA);
  if (nB) atomicAdd(&hB, nB);
#pragma unroll
  for (int o = 32; o > 0; o >>= 1) {
    aL += __shfl_down(aL, o); aI += __shfl_down(aI, o); aP += __shfl_down(aP, o);
  }
  int wid = tid >> 6, lane = tid & 63;
  if (lane == 0) { dred[wid] = aL; dred[4 + wid] = aI; dred[8 + wid] = aP; }
  __syncthreads();
  // per-block partials: plain stores, every slot written -> no pre-zero needed
  if (tid < 8) {
    pcnt[bid * 20 + tid]     = hc[tid] + hc[8 + tid] + hc[16 + tid] + hc[24 + tid];
    pcnt[bid * 20 + 8 + tid] = ht[tid] + ht[8 + tid] + ht[16 + tid] + ht[24 + tid];
  }
  if (tid == 0) {
    pcnt[bid * 20 + 16] = hA; pcnt[bid * 20 + 17] = hB;
    pcnt[bid * 20 + 18] = 0u; pcnt[bid * 20 + 19] = 0u;
    pdbl[bid * 3 + 0] = dred[0] + dred[1] + dred[2] + dred[3];
    pdbl[bid * 3 + 1] = dred[4] + dred[5] + dred[6] + dred[7];
    pdbl[bid * 3 + 2] = dred[8] + dred[9] + dred[10] + dred[11];
  }
}

__global__ __launch_bounds__(256, 2) void k_uf(
    const unsigned char* __restrict__ pk, int* __restrict__ parent,
    unsigned* __restrict__ stats, const unsigned* __restrict__ pcnt,
    int N, int nbam) {
  __shared__ unsigned nc[8], tot[18];
  __shared__ int lastF;
  int tid = threadIdx.x;
  int n4 = N >> 2, gsz = gridDim.x * blockDim.x;
  // ---- merge ------------------------------------------------------------
  for (int i4 = blockIdx.x * blockDim.x + tid; i4 < n4; i4 += gsz) {
    int i = i4 << 2;
    int hw = i & HWMASK;
    uchar4 a = *(const uchar4*)(pk + i);
    unsigned char ca[4] = {(unsigned char)(a.x & 7), (unsigned char)(a.y & 7),
                           (unsigned char)(a.z & 7), (unsigned char)(a.w & 7)};
    if (ca[0] && ca[0] == ca[1]) unite(parent, i,     i + 1);
    if (ca[1] && ca[1] == ca[2]) unite(parent, i + 1, i + 2);
    if (ca[2] && ca[2] == ca[3]) unite(parent, i + 2, i + 3);
    if ((hw & 511) < 508) {
      unsigned char nx = pk[i + 4] & 7;
      if (ca[3] && ca[3] == nx) unite(parent, i + 3, i + 4);
    }
    if ((hw >> 9) < 511) {
      uchar4 d = *(const uchar4*)(pk + i + 512);
      unsigned char da[4] = {(unsigned char)(d.x & 7), (unsigned char)(d.y & 7),
                             (unsigned char)(d.z & 7), (unsigned char)(d.w & 7)};
#pragma unroll
      for (int j = 0; j < 4; ++j)
        if (ca[j] && ca[j] == da[j]) unite(parent, i + j, i + j + 512);
    }
  }
  __syncthreads();   // drains vmcnt -> this block's CAS/AS complete at LLC
  // ---- arrive+spin grid barrier (co-residency: launch_bounds(256,2)) -----
  if (tid == 0) {
    if (ARRIVE(&stats[76]) == gridDim.x - 1) REL(&stats[90], 1u);
    else while (AL(&stats[90]) == 0u) __builtin_amdgcn_s_sleep(2);
  }
  __syncthreads();
  // ---- flatten: atomic loads (no boundary flush inside a fused kernel) ---
  if (tid < 8) nc[tid] = 0;
  __syncthreads();
  for (int i4 = blockIdx.x * blockDim.x + tid; i4 < n4; i4 += gsz) {
    int i = i4 << 2;
    uchar4 a = *(const uchar4*)(pk + i);
    unsigned char ca[4] = {(unsigned char)(a.x & 7), (unsigned char)(a.y & 7),
                           (unsigned char)(a.z & 7), (unsigned char)(a.w & 7)};
    int pa[4];
#pragma unroll
    for (int j = 0; j < 4; ++j) {
      pa[j] = i + j;
      if (!ca[j]) continue;
      int x = AL(&parent[i + j]);
      if (x == i + j) { atomicAdd(&nc[ca[j]], 1u); continue; }  // representative
      // read-only chase via coherent loads; values only ever move toward root
      while (true) { int nx = AL(&parent[x]); if (nx == x) break; x = nx; }
      pa[j] = x;
    }
    *(int4*)(parent + i) = make_int4(pa[0], pa[1], pa[2], pa[3]);
  }
  __syncthreads();
  if (tid < 8 && nc[tid]) atomicAdd(&stats[16 + tid], nc[tid]);
  __syncthreads();
  if (tid == 0) lastF = (ARRIVE(&stats[85]) == gridDim.x - 1) ? 1 : 0;
  __syncthreads();
  if (!lastF) return;
  // ---- last block: reduce partials (ALL nbam=1024 of them) ---------------
  unsigned S[18];
#pragma unroll
  for (int k = 0; k < 18; ++k) S[k] = 0u;
  for (int b = tid; b < nbam; b += 256) {
    const unsigned* p = pcnt + b * 20;
#pragma unroll
    for (int k = 0; k < 18; ++k) S[k] += p[k];
  }
  if (tid < 18) tot[tid] = 0u;
  __syncthreads();
#pragma unroll
  for (int k = 0; k < 18; ++k) {
    unsigned s = S[k];
#pragma unroll
    for (int o = 32; o > 0; o >>= 1) s += __shfl_down(s, o);
    if ((tid & 63) == 0 && s) atomicAdd(&tot[k], s);
  }
  __syncthreads();
  if (tid != 0) return;
  // ---- scalars (single thread) ------------------------------------------
  float prodf[8]; int last_i = 1; unsigned pb = 0;
  for (int v = 1; v < 8; ++v) {
    unsigned cntv = tot[v], ncv = AL(&stats[16 + v]);
    prodf[v] = 0.0f;
    if (cntv) {
      prodf[v] = __fmul_rn((float)ncv, (float)last_i);   // exact ref rounding
      pb |= 1u << v;
      last_i += (int)ncv + ((cntv < (unsigned)N) ? 1 : 0);  // + has_bg
    }
    stats[24 + v] = __float_as_uint(prodf[v]);
  }
  float ph0 = 0.0f;   // background key (min key: rounding is monotone)
  for (int v = 1; v < 8; ++v) if (pb & (1u << v)) ph0 = __fadd_rn(ph0, prodf[v]);
  unsigned ab = 0;
  for (int t = 1; t < 8; ++t) {
    unsigned n = tot[8 + t];
    stats[8 + t] = n;
    ((int*)stats)[48 + t] = n ? (int)((n - 1) >> 1) : -1;   // lower-median rank
    if (n) ab |= 1u << t;
  }
  stats[8] = tot[8];
  stats[34] = tot[16]; stats[35] = tot[17];
  stats[32] = pb; stats[33] = ab;
  unsigned pbits = __float_as_uint(ph0);
  stats[36] = pbits;
  // key-code window bound: codes in (ph0, ph0+2^20] <= 2^(43-e), e=exp(ph0)
  unsigned c;
  if (pbits == 0) c = 64u;
  else {
    int e = (int)(pbits >> 23) - 127;
    int sh = 43 - e;
    if (sh <= 0) c = 64u;
    else if (sh >= 31) c = 0x7FFFFFFFu;
    else c = (1u << sh) + 64u;
  }
  int bl = 32 - __clz((int)c);
  stats[37] = (bl > 8) ? (unsigned)(bl - 8) : 0u;   // s1 for 8-bit digits
}

// Sum 8 ghist replicas, scan 256 bins, pick the bin holding rank krem[t].
static __device__ void scan_select(unsigned* __restrict__ stats,
                                   const unsigned* __restrict__ ghist,
                                   unsigned abm, int s_cur, unsigned* lh) {
  int tid = threadIdx.x;
  for (int t = 1; t < 8; ++t) {
    if (!(abm >> t & 1u)) continue;
    int k = (int)AL(&stats[48 + t]);
    unsigned cnt = 0;
#pragma unroll
    for (int r = 0; r < 8; ++r)
      cnt += AL(&ghist[r * 1792 + ((t - 1) << 8) + tid]);
    lh[tid] = cnt;
    __syncthreads();
    for (int o = 1; o < 256; o <<= 1) {   // inclusive Hillis-Steele
      unsigned v = (tid >= o) ? lh[tid - o] : 0u;
      __syncthreads();
      lh[tid] += v;
      __syncthreads();
    }
    unsigned incl = lh[tid], excl = incl - cnt;
    if ((unsigned)k >= excl && (unsigned)k < incl) {   // unique owner
      atomicOr(&stats[40 + t], ((unsigned)tid) << s_cur);
      AS(&stats[48 + t], (unsigned)(k - (int)excl));
    }
    __syncthreads();
  }
}

__global__ __launch_bounds__(256, 2) void k_phase2(
    const unsigned char* __restrict__ pk, const int* __restrict__ parent,
    unsigned* __restrict__ stats, unsigned* __restrict__ ghist,
    const double* __restrict__ pdbl, float* __restrict__ out, int N, int nbam) {
  __shared__ unsigned lh[1792];
  __shared__ float sprod[8];
  __shared__ unsigned sw[32];
  __shared__ double dred[12];
  int tid = threadIdx.x;
  if (tid < 8) sprod[tid] = __uint_as_float(stats[24 + tid]);
  if (tid == 0) { sw[0] = stats[32]; sw[1] = stats[33]; sw[2] = stats[36]; sw[3] = stats[37]; }
  for (int j = tid; j < 1792; j += 256) lh[j] = 0u;
  __syncthreads();
  unsigned pb = sw[0], ab = sw[1], ph0 = sw[2];
  int s1 = (int)sw[3];
  unsigned rep = (blockIdx.x & 7) * 1792u;
  int n4 = N >> 2, gsz = gridDim.x * blockDim.x;
  // ---- keys in registers + radix pass 1 ---------------------------------
  unsigned kk[8];
  unsigned char tv8[8];
#pragma unroll
  for (int q = 0; q < 2; ++q) {
    int i4 = blockIdx.x * blockDim.x + tid + q * gsz;
    if (i4 < n4) {
      int i = i4 << 2;
      int4 pr = *(const int4*)(parent + i);
      uchar4 pv = *(const uchar4*)(pk + i);
      int parr[4] = {pr.x, pr.y, pr.z, pr.w};
      unsigned char pa[4] = {pv.x, pv.y, pv.z, pv.w};
#pragma unroll
      for (int j = 0; j < 4; ++j) {
        int c = pa[j] & 7, t = pa[j] >> 3;
        float lab = c ? (float)(parr[j] + 1) : 0.0f;   // < 2^24, exact
        float ph = 0.0f;
#pragma unroll
        for (int v = 1; v < 8; ++v) {                  // exact numpy op order
          if (pb & (1u << v)) {
            float term = sprod[v];
            if (c == v) term = __fadd_rn(lab, term);
            ph = __fadd_rn(ph, term);
          }
        }
        unsigned kb = __float_as_uint(ph);
        kk[q * 4 + j] = kb; tv8[q * 4 + j] = (unsigned char)t;
        if (t && (ab >> t & 1u)) {
          unsigned off = kb - ph0;                     // >= 0 by monotonicity
          unsigned bin = off >> s1;
          if (bin > 255u) bin = 255u;
          atomicAdd(&lh[((t - 1) << 8) | bin], 1u);
        }
      }
    } else {
#pragma unroll
      for (int j = 0; j < 4; ++j) { kk[q * 4 + j] = 0xFFFFFFFFu; tv8[q * 4 + j] = 0; }
    }
  }
  __syncthreads();
  for (int j = tid; j < 1792; j += 256) {
    unsigned v = lh[j];
    if (v) atomicAdd(&ghist[rep + j], v);
  }
  __syncthreads();
  if (tid == 0) sw[4] = (ARRIVE(&stats[77]) == gridDim.x - 1) ? 1u : 0u;
  __syncthreads();
  if (sw[4]) {
    scan_select(stats, ghist, ab, s1, lh);
    if (tid == 0) AS(&stats[38], (s1 == 0) ? 1u : 0u);
    if (s1 > 0)   // atomic stores: plain stores could sit dirty in local L2
      for (int j = tid; j < 14336; j += 256) AS(&ghist[j], 0u);
    __syncthreads();
    if (tid == 0) REL(&stats[39], 1u);
  } else {
    if (tid == 0) while (AL(&stats[39]) < 1u) __builtin_amdgcn_s_sleep(2);
    __syncthreads();
  }
  // ---- rare fallback passes ---------------------------------------------
  if (tid == 0) sw[5] = AL(&stats[38]);
  __syncthreads();
  if (!sw[5]) {
    for (int pass = 2; pass <= 4; ++pass) {
      int sprev = s1 - 8 * (pass - 2); if (sprev < 0) sprev = 0;
      int scur  = s1 - 8 * (pass - 1); if (scur  < 0) scur  = 0;
      unsigned maskhi = 0xFFFFFFFFu << sprev;
      if (tid < 8) sw[8 + tid] = AL(&stats[40 + tid]);
      for (int j = tid; j < 1792; j += 256) lh[j] = 0u;
      __syncthreads();
#pragma unroll
      for (int e = 0; e < 8; ++e) {
        int t = tv8[e];
        if (t && (ab >> t & 1u)) {
          unsigned off = kk[e] - ph0;
          if (((off ^ sw[8 + t]) & maskhi) == 0u)
            atomicAdd(&lh[((t - 1) << 8) | ((off >> scur) & 255u)], 1u);
        }
      }
      __syncthreads();
      for (int j = tid; j < 1792; j += 256) {
        unsigned v = lh[j];
        if (v) atomicAdd(&ghist[rep + j], v);
      }
      __syncthreads();
      if (tid == 0) sw[6] = (ARRIVE(&stats[76 + pass]) == gridDim.x - 1) ? 1u : 0u;
      __syncthreads();
      if (sw[6]) {
        scan_select(stats, ghist, ab, scur, lh);
        if (scur > 0)
          for (int j = tid; j < 14336; j += 256) AS(&ghist[j], 0u);
        __syncthreads();
        if (tid == 0) REL(&stats[39], (unsigned)pass);
      } else {
        if (tid == 0)
          while (AL(&stats[39]) < (unsigned)pass) __builtin_amdgcn_s_sleep(2);
        __syncthreads();
      }
      if (scur == 0) break;
    }
  }
  // ---- median-match counts from register keys ---------------------------
  if (tid < 8) { lh[tid] = 0u; lh[8 + tid] = 0u; sw[20 + tid] = ph0 + AL(&stats[40 + tid]); }
  __syncthreads();
#pragma unroll
  for (int e = 0; e < 8; ++e) {
    unsigned kb = kk[e];
    int t = tv8[e];
#pragma unroll
    for (int tt = 1; tt < 8; ++tt) {
      if ((ab >> tt & 1u) && kb == sw[20 + tt]) {
        atomicAdd(&lh[8 + tt], 1u);
        if (t == tt) atomicAdd(&lh[tt], 1u);
      }
    }
  }
  __syncthreads();
  if (tid >= 1 && tid < 8) {
    if (lh[8 + tid]) atomicAdd(&stats[64 + tid], lh[8 + tid]);   // |full_med|
    if (lh[tid])     atomicAdd(&stats[56 + tid], lh[tid]);       // n11
  }
  __syncthreads();
  if (tid == 0) sw[7] = (ARRIVE(&stats[84]) == gridDim.x - 1) ? 1u : 0u;
  __syncthreads();
  if (!sw[7]) return;
  // ---- finalize (last block) --------------------------------------------
  double vL = 0.0, vI = 0.0, vP = 0.0;
  for (int b = tid; b < nbam; b += 256) {
    vL += pdbl[b * 3]; vI += pdbl[b * 3 + 1]; vP += pdbl[b * 3 + 2];
  }
#pragma unroll
  for (int o = 32; o > 0; o >>= 1) {
    vL += __shfl_down(vL, o); vI += __shfl_down(vI, o); vP += __shfl_down(vP, o);
  }
  int wid = tid >> 6, lane = tid & 63;
  if (lane == 0) { dred[wid] = vL; dred[4 + wid] = vI; dred[8 + wid] = vP; }
  __syncthreads();
  if (tid != 0) return;
  vL = dred[0] + dred[1] + dred[2] + dred[3];
  vI = dred[4] + dred[5] + dred[6] + dred[7];
  vP = dred[8] + dred[9] + dred[10] + dred[11];
  double Nd = (double)N;
  const float e32 = 1e-7f;
  const float c1 = 1.0f - e32;
  const float omc1 = 1.0f - c1;
  double lp1 = log((double)c1);
  double lp0 = log((double)e32);
  double l01 = log((double)omc1);
  double l00 = lp1;
  double L = vL + (double)stats[34] * lp0 + (double)stats[35] * l00;
  double res = -L / Nd;                                               // bce_bg
  res += 1.0 - (2.0 * vI + 1.0) / (vP + (double)stats[8] + 1.0);      // dice_bg
  for (int t = 1; t < 8; ++t) {
    if (ab >> t & 1u) {
      double a = (double)AL(&stats[56 + t]);
      double f = (double)AL(&stats[64 + t]);
      double n = (double)stats[8 + t];
      double bce = -(a * lp1 + (n - a) * lp0 + (f - a) * l01 + (Nd - n - f + a) * l00) / Nd;
      double dice = 1.0 - (2.0 * a + 1.0) / (f + n + 1.0);
      res += bce + dice;
    }
  }
  int nu = (stats[8] > 0) ? 1 : 0;
  for (int t = 1; t < 8; ++t) nu += (stats[8 + t] > 0) ? 1 : 0;
  out[0] = (float)(res / ((double)nu + 1.0));
}

extern "C" void kernel_launch(void* const* d_in, const int* in_sizes, int n_in,
                              void* d_out, int out_size, void* d_ws, size_t ws_size,
                              hipStream_t stream) {
  const float* pred = (const float*)d_in[0];   // [B,8,512,512] f32
  const int* tgt = (const int*)d_in[1];        // [B,1,512,512] i32
  int N = in_sizes[1];                         // B*H*W
  char* ws = (char*)d_ws;
  int* parent = (int*)ws;
  unsigned char* pk = (unsigned char*)(ws + (size_t)N * 4);
  unsigned* stats = (unsigned*)(ws + (size_t)N * 5);
  unsigned* ghist = stats + 8192;
  unsigned* pcnt = stats + 22528;
  double* pdbl = (double*)(stats + 43008);
  float* out = (float*)d_out;
  int nbam = 1024;

  k_argmax<<<nbam, 256, 0, stream>>>(pred, tgt, parent, pk, stats, pcnt, pdbl, N);
  k_uf<<<512, 256, 0, stream>>>(pk, parent, stats, pcnt, N, nbam);
  k_phase2<<<512, 256, 0, stream>>>(pk, parent, stats, ghist, pdbl, out, N, nbam);
}